// Round 5
// baseline (315.246 us; speedup 1.0000x reference)
//
#include <hip/hip_runtime.h>
#include <hip/hip_bf16.h>

// Problem constants
#define BB 2
#define SS 1024
#define DD 768
#define HH 12
#define HD 64
#define DFF 3072
#define EPS 1e-5f

typedef unsigned short ushort_t;
typedef unsigned char uchar_t;
using short8 = __attribute__((ext_vector_type(8))) short;
using f32x4  = __attribute__((ext_vector_type(4))) float;

__device__ __forceinline__ ushort_t f2bf_rne(float f) {
    union { float f; unsigned u; } x; x.f = f;
    unsigned r = x.u + 0x7fff + ((x.u >> 16) & 1);
    return (ushort_t)(r >> 16);
}
__device__ __forceinline__ float bf2f(short u) {
    union { unsigned i; float f; } x;
    x.i = ((unsigned)(ushort_t)u) << 16;
    return x.f;
}

// ---------------------------------------------------------------------------
// fp32 -> bf16 conversion (vectorized), n4 = n/4
// ---------------------------------------------------------------------------
__global__ __launch_bounds__(256) void cvt_bf16(
    const float* __restrict__ in, ushort_t* __restrict__ out, int n4)
{
    int i = blockIdx.x * 256 + threadIdx.x;
    if (i < n4) {
        float4 v = ((const float4*)in)[i];
        ushort4 o;
        o.x = f2bf_rne(v.x); o.y = f2bf_rne(v.y);
        o.z = f2bf_rne(v.z); o.w = f2bf_rne(v.w);
        ((ushort4*)out)[i] = o;
    }
}

// ---------------------------------------------------------------------------
// Pack rel+mask into lane-permuted int8 codes:
//   codes[((b*S+q)*16 + kt)*16 + l15] packs nt=0..3 bytes,
//   code = mask[b][k] ? 3 : rel[b][q][k]+1, k = kt*64 + nt*16 + l15.
// ---------------------------------------------------------------------------
__global__ __launch_bounds__(256) void build_codes(
    const int* __restrict__ rel, const uchar_t* __restrict__ mask,
    unsigned* __restrict__ codes)
{
    int tid = blockIdx.x * 256 + threadIdx.x;      // B*S*16*16 total
    int l15 = tid & 15;
    int kt  = (tid >> 4) & 15;
    int q   = (tid >> 8) & (SS - 1);
    int b   = tid >> 18;
    const int* rrow = rel + ((size_t)(b * SS + q)) * SS + kt * 64 + l15;
    const uchar_t* mrow = mask + (size_t)b * SS + kt * 64 + l15;
    unsigned o = 0;
#pragma unroll
    for (int nt = 0; nt < 4; ++nt) {
        unsigned c = mrow[nt * 16] ? 3u : (unsigned)(rrow[nt * 16] + 1);
        o |= c << (8 * nt);
    }
    codes[((size_t)(b * SS + q) * 16 + kt) * 16 + l15] = o;
}

// ---------------------------------------------------------------------------
// LayerNorm: fp32 in -> bf16 out. One block per row, 256 threads, D=768.
// ---------------------------------------------------------------------------
__global__ __launch_bounds__(256) void ln_kernel_bf(
    const float* __restrict__ x, const float* __restrict__ g,
    const float* __restrict__ b, ushort_t* __restrict__ y)
{
    const int row = blockIdx.x;
    const float* xr = x + (size_t)row * DD;
    float s = 0.f, ss = 0.f;
    for (int i = threadIdx.x; i < DD; i += 256) {
        float v = xr[i];
        s += v; ss += v * v;
    }
    for (int off = 32; off; off >>= 1) {
        s  += __shfl_down(s,  off);
        ss += __shfl_down(ss, off);
    }
    __shared__ float reds[4], redss[4], bc[2];
    int t = threadIdx.x;
    if ((t & 63) == 0) { reds[t >> 6] = s; redss[t >> 6] = ss; }
    __syncthreads();
    if (t == 0) {
        float S1 = reds[0] + reds[1] + reds[2] + reds[3];
        float S2 = redss[0] + redss[1] + redss[2] + redss[3];
        float mean = S1 / DD;
        float var = S2 / DD - mean * mean;
        bc[0] = mean;
        bc[1] = rsqrtf(var + EPS);
    }
    __syncthreads();
    float mean = bc[0], inv = bc[1];
    ushort_t* yr = y + (size_t)row * DD;
    for (int i = threadIdx.x; i < DD; i += 256) {
        yr[i] = f2bf_rne((xr[i] - mean) * inv * g[i] + b[i]);
    }
}

// ---------------------------------------------------------------------------
// init_out: out = resid + b2 (seeds the MLP2 split-K atomic accumulator)
// ---------------------------------------------------------------------------
__global__ __launch_bounds__(256) void init_out_kernel(
    const float* __restrict__ resid, const float* __restrict__ b2,
    float* __restrict__ out, int n4)
{
    int i = blockIdx.x * 256 + threadIdx.x;
    if (i < n4) {
        int col4 = (i * 4) % DD;
        float4 r = ((const float4*)resid)[i];
        float4 b = *(const float4*)(b2 + col4);
        r.x += b.x; r.y += b.y; r.z += b.z; r.w += b.w;
        ((float4*)out)[i] = r;
    }
}

// ---------------------------------------------------------------------------
// 1-wave GEMM, no LDS, no barriers. C[M,N] = act(A[M,K] @ W[N,K]^T (+bias)
// (+resid)), bf16 in, fp32 acc. Each wave computes a 64x64 tile = 4x4 MFMA
// sub-tiles of 16x16x32. A/B fragments are loaded DIRECTLY from global as
// b128s (lane l15 = row, quad = k-chunk; 16-B aligned, 16 full 64-B lines
// per instr). Rotating 3-buffer register pipeline prefetches 2 iters ahead.
// grid = (N/64, M/64, SPLITK); ATOMIC path does fp32 atomicAdd into Cout.
// ---------------------------------------------------------------------------
template <bool RELU, bool OUT_BF16, bool HAS_BIAS, bool HAS_RES, bool ATOMIC>
__global__ __launch_bounds__(64) void gemm_wave(
    const ushort_t* __restrict__ A, const ushort_t* __restrict__ W,
    const float* __restrict__ bias, const float* __restrict__ resid,
    void* __restrict__ Cout, int M, int N, int K, int Ksplit)
{
    const int n0 = blockIdx.x * 64;
    const int m0 = blockIdx.y * 64;
    const int kb = blockIdx.z * Ksplit;
    const int l15  = threadIdx.x & 15;
    const int quad = threadIdx.x >> 4;

    const ushort_t* aP[4];
    const ushort_t* bP[4];
#pragma unroll
    for (int i = 0; i < 4; ++i) {
        aP[i] = A + (size_t)(m0 + i * 16 + l15) * K + kb + quad * 8;
        bP[i] = W + (size_t)(n0 + i * 16 + l15) * K + kb + quad * 8;
    }

    const int nIter = Ksplit >> 5;   // 12 or 24 -> divisible by 3

    f32x4 acc[4][4] = {};
    short8 aF[3][4], bF[3][4];
#pragma unroll
    for (int i = 0; i < 4; ++i) {
        aF[0][i] = *(const short8*)(aP[i]);
        bF[0][i] = *(const short8*)(bP[i]);
        aF[1][i] = *(const short8*)(aP[i] + 32);
        bF[1][i] = *(const short8*)(bP[i] + 32);
    }

    for (int base = 0; base < nIter; base += 3) {
#pragma unroll
        for (int j = 0; j < 3; ++j) {
            const int nb = (j + 2) % 3;          // compile-time per unrolled j
            const int pre = base + j + 2;
            if (pre < nIter) {
                const int off = pre * 32;
#pragma unroll
                for (int i = 0; i < 4; ++i) {
                    aF[nb][i] = *(const short8*)(aP[i] + off);
                    bF[nb][i] = *(const short8*)(bP[i] + off);
                }
            }
#pragma unroll
            for (int i = 0; i < 4; ++i)
#pragma unroll
                for (int jj = 0; jj < 4; ++jj)
                    acc[i][jj] = __builtin_amdgcn_mfma_f32_16x16x32_bf16(
                        aF[j][i], bF[j][jj], acc[i][jj], 0, 0, 0);
        }
    }

    // epilogue: C/D layout col=lane&15, row=(lane>>4)*4+reg
#pragma unroll
    for (int i = 0; i < 4; ++i) {
        const int row = m0 + i * 16 + quad * 4;
#pragma unroll
        for (int j = 0; j < 4; ++j) {
            const int col = n0 + j * 16 + l15;
            const float bv = HAS_BIAS ? bias[col] : 0.f;
#pragma unroll
            for (int r = 0; r < 4; ++r) {
                float v = acc[i][j][r] + bv;
                if (HAS_RES) v += resid[(size_t)(row + r) * N + col];
                if (RELU) v = fmaxf(v, 0.f);
                if (ATOMIC)
                    atomicAdd(&((float*)Cout)[(size_t)(row + r) * N + col], v);
                else if (OUT_BF16)
                    ((ushort_t*)Cout)[(size_t)(row + r) * N + col] = f2bf_rne(v);
                else
                    ((float*)Cout)[(size_t)(row + r) * N + col] = v;
            }
        }
    }
}

// ---------------------------------------------------------------------------
// MFMA flash attention (unchanged from round 4). Block per (b,h,64-q tile).
// ---------------------------------------------------------------------------
__global__ __launch_bounds__(256) void attn_mfma_kernel(
    const ushort_t* __restrict__ qkv,      // (B*S, 2304) bf16
    const unsigned* __restrict__ codes,    // packed rel/mask codes
    const float* __restrict__ rel_A,       // (3, 64) fp32
    ushort_t* __restrict__ attnout)        // (B*S, 768) bf16
{
    __shared__ __align__(16) ushort_t Ks[64 * 64];
    __shared__ __align__(16) unsigned Vt2[64 * 36];
    __shared__ __align__(16) ushort_t Ps[64 * 72];
    __shared__ __align__(16) float r3s[64][4];

    const int bx = blockIdx.x;
    const int qt = bx & 15;
    const int h  = (bx >> 4) % HH;
    const int b  = bx / (16 * HH);
    const int q0 = qt * 64;
    const int t  = threadIdx.x;
    const int w  = t >> 6;
    const int l  = t & 63;
    const int l15  = l & 15;
    const int quad = l >> 4;

    const size_t qrow = (size_t)(b * SS + q0 + w * 16 + l15) * (3 * DD) + h * HD;
    const short8 qf0 = *(const short8*)(qkv + qrow + quad * 8);
    const short8 qf1 = *(const short8*)(qkv + qrow + 32 + quad * 8);

    {
        float rv[3];
#pragma unroll
        for (int c = 0; c < 3; ++c) {
            const float* a = rel_A + c * HD + quad * 8;
            float acc = 0.f;
#pragma unroll
            for (int j = 0; j < 8; ++j) acc += bf2f(qf0[j]) * a[j];
#pragma unroll
            for (int j = 0; j < 8; ++j) acc += bf2f(qf1[j]) * a[32 + j];
            acc += __shfl_xor(acc, 16);
            acc += __shfl_xor(acc, 32);
            rv[c] = acc;
        }
        if (quad == 0) {
            float4 f4 = make_float4(rv[0], rv[1], rv[2], -2.4e31f);
            *(float4*)&r3s[w * 16 + l15][0] = f4;
        }
    }
    __syncthreads();
    float4 r3v[4];
#pragma unroll
    for (int reg = 0; reg < 4; ++reg)
        r3v[reg] = *(const float4*)&r3s[w * 16 + quad * 4 + reg][0];

    float m_run[4] = {-1e30f, -1e30f, -1e30f, -1e30f};
    float l_run[4] = {0.f, 0.f, 0.f, 0.f};
    f32x4 oacc[4] = {};

    for (int kt = 0; kt < SS / 64; ++kt) {
        const int k0 = kt * 64;
        __syncthreads();
        {
            const int r  = t >> 3;
            const int cp = t & 7;
            const int cl  = cp ^ (r & 7);
            const ushort_t* g = qkv + (size_t)(b * SS + k0 + r) * (3 * DD) + DD + h * HD + cl * 8;
            __builtin_amdgcn_global_load_lds(
                (const __attribute__((address_space(1))) unsigned*)g,
                (__attribute__((address_space(3))) unsigned*)(Ks + (size_t)t * 8), 16, 0, 0);
            const int r2  = r + 32;
            const int cl2 = cp ^ (r2 & 7);
            const ushort_t* g2 = qkv + (size_t)(b * SS + k0 + r2) * (3 * DD) + DD + h * HD + cl2 * 8;
            __builtin_amdgcn_global_load_lds(
                (const __attribute__((address_space(1))) unsigned*)g2,
                (__attribute__((address_space(3))) unsigned*)(Ks + (size_t)(t + 256) * 8), 16, 0, 0);
        }
        {
            const int kp = t >> 3;
            const int dg = t & 7;
            const ushort_t* g = qkv + (size_t)(b * SS + k0 + 2 * kp) * (3 * DD) + 2 * DD + h * HD + dg * 8;
            short8 va = *(const short8*)g;
            short8 vb = *(const short8*)(g + 3 * DD);
            const int kps = kp ^ ((dg & 7) * 4);
#pragma unroll
            for (int i = 0; i < 8; ++i)
                Vt2[(size_t)(dg * 8 + i) * 36 + kps] =
                    (unsigned)(ushort_t)va[i] | ((unsigned)(ushort_t)vb[i] << 16);
        }
        __syncthreads();

        f32x4 sacc[4] = {};
#pragma unroll
        for (int kc = 0; kc < 2; ++kc) {
            const short8 qv = kc ? qf1 : qf0;
#pragma unroll
            for (int nt = 0; nt < 4; ++nt) {
                const int row = nt * 16 + l15;
                const int cp  = (kc * 4 + quad) ^ (row & 7);
                const short8 kf = *(const short8*)(Ks + (size_t)row * 64 + cp * 8);
                sacc[nt] = __builtin_amdgcn_mfma_f32_16x16x32_bf16(qv, kf, sacc[nt], 0, 0, 0);
            }
        }

        float alpha[4];
#pragma unroll
        for (int reg = 0; reg < 4; ++reg) {
            const int qloc = w * 16 + quad * 4 + reg;
            const unsigned cds = codes[((size_t)(b * SS + q0 + qloc) * 16 + kt) * 16 + l15];
            float lv[4];
#pragma unroll
            for (int nt = 0; nt < 4; ++nt) {
                const unsigned c = (cds >> (8 * nt)) & 0xff;
                const float4 r4 = r3v[reg];
                float rvv = (c == 0) ? r4.x : (c == 1) ? r4.y : (c == 2) ? r4.z : r4.w;
                lv[nt] = (sacc[nt][reg] + rvv) * 0.125f;
            }
            float tm = fmaxf(fmaxf(lv[0], lv[1]), fmaxf(lv[2], lv[3]));
            tm = fmaxf(tm, __shfl_xor(tm, 1));
            tm = fmaxf(tm, __shfl_xor(tm, 2));
            tm = fmaxf(tm, __shfl_xor(tm, 4));
            tm = fmaxf(tm, __shfl_xor(tm, 8));
            const float mn = fmaxf(m_run[reg], tm);
            alpha[reg] = __expf(m_run[reg] - mn);
            m_run[reg] = mn;
            float ts = 0.f;
#pragma unroll
            for (int nt = 0; nt < 4; ++nt) {
                const float p = __expf(lv[nt] - mn);
                ts += p;
                Ps[(size_t)qloc * 72 + nt * 16 + l15] = f2bf_rne(p);
            }
            ts += __shfl_xor(ts, 1);
            ts += __shfl_xor(ts, 2);
            ts += __shfl_xor(ts, 4);
            ts += __shfl_xor(ts, 8);
            l_run[reg] = l_run[reg] * alpha[reg] + ts;
        }
#pragma unroll
        for (int dt = 0; dt < 4; ++dt)
#pragma unroll
            for (int reg = 0; reg < 4; ++reg)
                oacc[dt][reg] *= alpha[reg];

#pragma unroll
        for (int kc = 0; kc < 2; ++kc) {
            const short8 pf = *(const short8*)(Ps + (size_t)(w * 16 + l15) * 72 + kc * 32 + quad * 8);
#pragma unroll
            for (int dt = 0; dt < 4; ++dt) {
                const int d  = dt * 16 + l15;
                const int dg = d >> 3;
                const int kps0 = (kc * 16 + quad * 4) ^ ((dg & 7) * 4);
                const short8 vf = *(const short8*)((const ushort_t*)&Vt2[(size_t)d * 36 + kps0]);
                oacc[dt] = __builtin_amdgcn_mfma_f32_16x16x32_bf16(pf, vf, oacc[dt], 0, 0, 0);
            }
        }
    }

#pragma unroll
    for (int reg = 0; reg < 4; ++reg) {
        const float inv = 1.0f / l_run[reg];
        const size_t orow = (size_t)(b * SS + q0 + w * 16 + quad * 4 + reg) * DD + h * HD;
#pragma unroll
        for (int dt = 0; dt < 4; ++dt)
            attnout[orow + dt * 16 + l15] = f2bf_rne(oacc[dt][reg] * inv);
    }
}

// ---------------------------------------------------------------------------
extern "C" void kernel_launch(void* const* d_in, const int* in_sizes, int n_in,
                              void* d_out, int out_size, void* d_ws, size_t ws_size,
                              hipStream_t stream) {
    const float* inp   = (const float*)d_in[0];
    const uchar_t* amask = (const uchar_t*)d_in[1];
    const int*   relm  = (const int*)d_in[2];
    const float* qkv_w = (const float*)d_in[3];
    const float* rel_A = (const float*)d_in[4];
    const float* o_w   = (const float*)d_in[5];
    const float* w1    = (const float*)d_in[6];
    const float* b1    = (const float*)d_in[7];
    const float* w2    = (const float*)d_in[8];
    const float* b2    = (const float*)d_in[9];
    const float* ln1_g = (const float*)d_in[10];
    const float* ln1_b = (const float*)d_in[11];
    const float* ln2_g = (const float*)d_in[12];
    const float* ln2_b = (const float*)d_in[13];
    float* out = (float*)d_out;

    const int BS = BB * SS;  // 2048 rows

    // workspace layout
    char* p = (char*)d_ws;
    ushort_t* x_bf   = (ushort_t*)p; p += (size_t)BS * DD * 2;
    ushort_t* att_bf = (ushort_t*)p; p += (size_t)BS * DD * 2;
    ushort_t* h_bf   = (ushort_t*)p; p += (size_t)BS * DD * 2;
    ushort_t* ff_bf  = (ushort_t*)p; p += (size_t)BS * DFF * 2;
    ushort_t* qkvw_bf= (ushort_t*)p; p += (size_t)3 * DD * DD * 2;
    ushort_t* ow_bf  = (ushort_t*)p; p += (size_t)DD * DD * 2;
    ushort_t* w1_bf  = (ushort_t*)p; p += (size_t)DFF * DD * 2;
    ushort_t* w2_bf  = (ushort_t*)p; p += (size_t)DD * DFF * 2;
    ushort_t* qkv_bf = (ushort_t*)p; p += (size_t)BS * 3 * DD * 2;
    float*    resid  = (float*)p;    p += (size_t)BS * DD * 4;
    unsigned* codes  = (unsigned*)p; p += (size_t)BB * SS * SS;   // 2 MB

    // 0. weight conversions fp32 -> bf16 + code packing
    {
        int n4;
        n4 = 3 * DD * DD / 4;
        cvt_bf16<<<(n4 + 255) / 256, 256, 0, stream>>>(qkv_w, qkvw_bf, n4);
        n4 = DD * DD / 4;
        cvt_bf16<<<(n4 + 255) / 256, 256, 0, stream>>>(o_w, ow_bf, n4);
        n4 = DFF * DD / 4;
        cvt_bf16<<<(n4 + 255) / 256, 256, 0, stream>>>(w1, w1_bf, n4);
        cvt_bf16<<<(n4 + 255) / 256, 256, 0, stream>>>(w2, w2_bf, n4);
        build_codes<<<(BB * SS * 256) / 256, 256, 0, stream>>>(relm, amask, codes);
    }

    // 1. LN1 -> bf16
    ln_kernel_bf<<<BS, 256, 0, stream>>>(inp, ln1_g, ln1_b, x_bf);

    // 2. QKV = x @ qkv_w.T -> bf16 : grid (36, 32), 1152 one-wave blocks
    gemm_wave<false, true, false, false, false>
        <<<dim3(3 * DD / 64, BS / 64, 1), 64, 0, stream>>>(
        x_bf, qkvw_bf, nullptr, nullptr, qkv_bf, BS, 3 * DD, DD, DD);

    // 3. MFMA flash attention -> bf16 : grid 384
    attn_mfma_kernel<<<BB * HH * (SS / 64), 256, 0, stream>>>(
        qkv_bf, codes, rel_A, att_bf);

    // 4. resid = inp + att @ o_w.T (fp32) : grid (12, 32), 384 blocks
    gemm_wave<false, false, false, true, false>
        <<<dim3(DD / 64, BS / 64, 1), 64, 0, stream>>>(
        att_bf, ow_bf, nullptr, inp, resid, BS, DD, DD, DD);

    // 5. LN2 -> bf16
    ln_kernel_bf<<<BS, 256, 0, stream>>>(resid, ln2_g, ln2_b, h_bf);

    // 6. ff = relu(h @ w1.T + b1) -> bf16 : grid (48, 32), 1536 blocks
    gemm_wave<true, true, true, false, false>
        <<<dim3(DFF / 64, BS / 64, 1), 64, 0, stream>>>(
        h_bf, w1_bf, b1, nullptr, ff_bf, BS, DFF, DD, DD);

    // 7a. out = resid + b2
    init_out_kernel<<<(BS * DD / 4 + 255) / 256, 256, 0, stream>>>(
        resid, b2, out, BS * DD / 4);

    // 7b. out += ff @ w2.T  (split-K x4, fp32 atomics) : grid (12, 32, 4)
    gemm_wave<false, false, false, false, true>
        <<<dim3(DD / 64, BS / 64, 4), 64, 0, stream>>>(
        ff_bf, w2_bf, nullptr, nullptr, out, BS, DD, DFF, DFF / 4);
}

// Round 6
// 293.957 us; speedup vs baseline: 1.0724x; 1.0724x over previous
//
#include <hip/hip_runtime.h>
#include <hip/hip_bf16.h>

// Problem constants
#define BB 2
#define SS 1024
#define DD 768
#define HH 12
#define HD 64
#define DFF 3072
#define EPS 1e-5f
#define BS2 (BB * SS)            // 2048
#define BSD ((size_t)BS2 * DD)   // 2048*768

typedef unsigned short ushort_t;
typedef unsigned char uchar_t;
using short8 = __attribute__((ext_vector_type(8))) short;
using f32x4  = __attribute__((ext_vector_type(4))) float;

__device__ __forceinline__ ushort_t f2bf_rne(float f) {
    union { float f; unsigned u; } x; x.f = f;
    unsigned r = x.u + 0x7fff + ((x.u >> 16) & 1);
    return (ushort_t)(r >> 16);
}
__device__ __forceinline__ float bf2f(short u) {
    union { unsigned i; float f; } x;
    x.i = ((unsigned)(ushort_t)u) << 16;
    return x.f;
}

// ---------------------------------------------------------------------------
// fp32 -> bf16 conversion (vectorized), n4 = n/4
// ---------------------------------------------------------------------------
__global__ __launch_bounds__(256) void cvt_bf16(
    const float* __restrict__ in, ushort_t* __restrict__ out, int n4)
{
    int i = blockIdx.x * 256 + threadIdx.x;
    if (i < n4) {
        float4 v = ((const float4*)in)[i];
        ushort4 o;
        o.x = f2bf_rne(v.x); o.y = f2bf_rne(v.y);
        o.z = f2bf_rne(v.z); o.w = f2bf_rne(v.w);
        ((ushort4*)out)[i] = o;
    }
}

// ---------------------------------------------------------------------------
// Pack rel+mask into lane-permuted int8 codes (see round 4).
// ---------------------------------------------------------------------------
__global__ __launch_bounds__(256) void build_codes(
    const int* __restrict__ rel, const uchar_t* __restrict__ mask,
    unsigned* __restrict__ codes)
{
    int tid = blockIdx.x * 256 + threadIdx.x;      // B*S*16*16 total
    int l15 = tid & 15;
    int kt  = (tid >> 4) & 15;
    int q   = (tid >> 8) & (SS - 1);
    int b   = tid >> 18;
    const int* rrow = rel + ((size_t)(b * SS + q)) * SS + kt * 64 + l15;
    const uchar_t* mrow = mask + (size_t)b * SS + kt * 64 + l15;
    unsigned o = 0;
#pragma unroll
    for (int nt = 0; nt < 4; ++nt) {
        unsigned c = mrow[nt * 16] ? 3u : (unsigned)(rrow[nt * 16] + 1);
        o |= c << (8 * nt);
    }
    codes[((size_t)(b * SS + q) * 16 + kt) * 16 + l15] = o;
}

// ---------------------------------------------------------------------------
// LayerNorm: fp32 in -> bf16 out. One block per row, 256 threads, D=768.
// ---------------------------------------------------------------------------
__global__ __launch_bounds__(256) void ln_kernel_bf(
    const float* __restrict__ x, const float* __restrict__ g,
    const float* __restrict__ b, ushort_t* __restrict__ y)
{
    const int row = blockIdx.x;
    const float* xr = x + (size_t)row * DD;
    float s = 0.f, ss = 0.f;
    for (int i = threadIdx.x; i < DD; i += 256) {
        float v = xr[i];
        s += v; ss += v * v;
    }
    for (int off = 32; off; off >>= 1) {
        s  += __shfl_down(s,  off);
        ss += __shfl_down(ss, off);
    }
    __shared__ float reds[4], redss[4], bc[2];
    int t = threadIdx.x;
    if ((t & 63) == 0) { reds[t >> 6] = s; redss[t >> 6] = ss; }
    __syncthreads();
    if (t == 0) {
        float S1 = reds[0] + reds[1] + reds[2] + reds[3];
        float S2 = redss[0] + redss[1] + redss[2] + redss[3];
        float mean = S1 / DD;
        float var = S2 / DD - mean * mean;
        bc[0] = mean;
        bc[1] = rsqrtf(var + EPS);
    }
    __syncthreads();
    float mean = bc[0], inv = bc[1];
    ushort_t* yr = y + (size_t)row * DD;
    for (int i = threadIdx.x; i < DD; i += 256) {
        yr[i] = f2bf_rne((xr[i] - mean) * inv * g[i] + b[i]);
    }
}

// ---------------------------------------------------------------------------
// init_out: out = resid + b2 (seeds the MLP2 split-K atomic accumulator)
// ---------------------------------------------------------------------------
__global__ __launch_bounds__(256) void init_out_kernel(
    const float* __restrict__ resid, const float* __restrict__ b2,
    float* __restrict__ out, int n4)
{
    int i = blockIdx.x * 256 + threadIdx.x;
    if (i < n4) {
        int col4 = (i * 4) % DD;
        float4 r = ((const float4*)resid)[i];
        float4 b = *(const float4*)(b2 + col4);
        r.x += b.x; r.y += b.y; r.z += b.z; r.w += b.w;
        ((float4*)out)[i] = r;
    }
}

// ---------------------------------------------------------------------------
// 2-wave GEMM: 128 threads; each wave computes the SAME 64x64 tile over a
// disjoint half of K (direct-global b128 fragment loads, depth-2 register
// pipeline, no LDS in the K-loop). Wave 1 dumps its fp32 acc to LDS; wave 0
// adds and runs the epilogue. grid = (N/64, M/64, Z); Ksplit = K/Z.
// ATOMIC: fp32 atomicAdd into pre-seeded Cout.
// ---------------------------------------------------------------------------
template <bool RELU, bool OUT_BF16, bool HAS_BIAS, bool ATOMIC>
__global__ __launch_bounds__(128) void gemm_wave2(
    const ushort_t* __restrict__ A, const ushort_t* __restrict__ W,
    const float* __restrict__ bias, void* __restrict__ Cout,
    int M, int N, int K, int Ksplit)
{
    __shared__ float red[64 * 64];   // 16 KB

    const int n0 = blockIdx.x * 64;
    const int m0 = blockIdx.y * 64;
    const int w  = threadIdx.x >> 6;
    const int l  = threadIdx.x & 63;
    const int l15  = l & 15;
    const int quad = l >> 4;
    const int K2 = Ksplit >> 1;
    const int kb = blockIdx.z * Ksplit + w * K2;

    const ushort_t* aP[4];
    const ushort_t* bP[4];
#pragma unroll
    for (int i = 0; i < 4; ++i) {
        aP[i] = A + (size_t)(m0 + i * 16 + l15) * K + kb + quad * 8;
        bP[i] = W + (size_t)(n0 + i * 16 + l15) * K + kb + quad * 8;
    }

    const int nIter = K2 >> 5;   // 12 or 6 (even)

    f32x4 acc[4][4] = {};
    short8 aF[2][4], bF[2][4];
#pragma unroll
    for (int i = 0; i < 4; ++i) {
        aF[0][i] = *(const short8*)(aP[i]);
        bF[0][i] = *(const short8*)(bP[i]);
    }

    for (int base = 0; base < nIter; base += 2) {
#pragma unroll
        for (int j = 0; j < 2; ++j) {
            const int pre = base + j + 1;
            if (pre < nIter) {
                const int off = pre * 32;
#pragma unroll
                for (int i = 0; i < 4; ++i) {
                    aF[j ^ 1][i] = *(const short8*)(aP[i] + off);
                    bF[j ^ 1][i] = *(const short8*)(bP[i] + off);
                }
            }
#pragma unroll
            for (int i = 0; i < 4; ++i)
#pragma unroll
                for (int jj = 0; jj < 4; ++jj)
                    acc[i][jj] = __builtin_amdgcn_mfma_f32_16x16x32_bf16(
                        aF[j][i], bF[j][jj], acc[i][jj], 0, 0, 0);
        }
    }

    // cross-wave combine through LDS (b32 lane-contiguous: conflict-free)
    if (w == 1) {
#pragma unroll
        for (int i = 0; i < 4; ++i)
#pragma unroll
            for (int j = 0; j < 4; ++j)
#pragma unroll
                for (int r = 0; r < 4; ++r)
                    red[(((i * 4 + j) * 4) + r) * 64 + l] = acc[i][j][r];
    }
    __syncthreads();
    if (w == 0) {
#pragma unroll
        for (int i = 0; i < 4; ++i)
#pragma unroll
            for (int j = 0; j < 4; ++j)
#pragma unroll
                for (int r = 0; r < 4; ++r)
                    acc[i][j][r] += red[(((i * 4 + j) * 4) + r) * 64 + l];

        // epilogue: C/D layout col=lane&15, row=(lane>>4)*4+reg
#pragma unroll
        for (int i = 0; i < 4; ++i) {
            const int row = m0 + i * 16 + quad * 4;
#pragma unroll
            for (int j = 0; j < 4; ++j) {
                const int col = n0 + j * 16 + l15;
                const float bv = HAS_BIAS ? bias[col] : 0.f;
#pragma unroll
                for (int r = 0; r < 4; ++r) {
                    float v = acc[i][j][r] + bv;
                    if (RELU) v = fmaxf(v, 0.f);
                    if (ATOMIC)
                        atomicAdd(&((float*)Cout)[(size_t)(row + r) * N + col], v);
                    else if (OUT_BF16)
                        ((ushort_t*)Cout)[(size_t)(row + r) * N + col] = f2bf_rne(v);
                    else
                        ((float*)Cout)[(size_t)(row + r) * N + col] = v;
                }
            }
        }
    }
}

// ---------------------------------------------------------------------------
// MFMA flash attention, K-SPLIT x2, NO online max (logits are small; masked
// entries hit a -2.4e31 sentinel -> exp = 0). No cross-lane ops in the
// k-loop; l reduced once at the end. Emits unnormalized O (fp32) + l
// partials; attn_merge normalizes. Block per (b, h, qtile, ks): grid 768.
// ---------------------------------------------------------------------------
__global__ __launch_bounds__(256) void attn_mfma_kernel(
    const ushort_t* __restrict__ qkv,      // (B*S, 2304) bf16
    const unsigned* __restrict__ codes,    // packed rel/mask codes
    const float* __restrict__ rel_A,       // (3, 64) fp32
    float* __restrict__ Opart,             // [2][BS*DD] fp32 unnormalized
    float* __restrict__ lpart)             // [2][BS*HH] fp32 row sums
{
    __shared__ __align__(16) ushort_t Ks[64 * 64];
    __shared__ __align__(16) unsigned Vt2[64 * 36];
    __shared__ __align__(16) ushort_t Ps[64 * 72];
    __shared__ __align__(16) float r3s[64][4];

    const int bx = blockIdx.x;
    const int ks = bx & 1;
    const int qt = (bx >> 1) & 15;
    const int h  = (bx >> 5) % HH;
    const int b  = bx / (32 * HH);
    const int q0 = qt * 64;
    const int t  = threadIdx.x;
    const int w  = t >> 6;
    const int l  = t & 63;
    const int l15  = l & 15;
    const int quad = l >> 4;

    const size_t qrow = (size_t)(b * SS + q0 + w * 16 + l15) * (3 * DD) + h * HD;
    const short8 qf0 = *(const short8*)(qkv + qrow + quad * 8);
    const short8 qf1 = *(const short8*)(qkv + qrow + 32 + quad * 8);

    {
        float rv[3];
#pragma unroll
        for (int c = 0; c < 3; ++c) {
            const float* a = rel_A + c * HD + quad * 8;
            float acc = 0.f;
#pragma unroll
            for (int j = 0; j < 8; ++j) acc += bf2f(qf0[j]) * a[j];
#pragma unroll
            for (int j = 0; j < 8; ++j) acc += bf2f(qf1[j]) * a[32 + j];
            acc += __shfl_xor(acc, 16);
            acc += __shfl_xor(acc, 32);
            rv[c] = acc;
        }
        if (quad == 0) {
            float4 f4 = make_float4(rv[0], rv[1], rv[2], -2.4e31f);
            *(float4*)&r3s[w * 16 + l15][0] = f4;
        }
    }
    __syncthreads();
    float4 r3v[4];
#pragma unroll
    for (int reg = 0; reg < 4; ++reg)
        r3v[reg] = *(const float4*)&r3s[w * 16 + quad * 4 + reg][0];

    float l_run[4] = {0.f, 0.f, 0.f, 0.f};
    f32x4 oacc[4] = {};

    for (int kt = ks * 8; kt < ks * 8 + 8; ++kt) {
        const int k0 = kt * 64;
        __syncthreads();
        // ---- stage K (XOR-swizzled chunks) ----
        {
            const int r  = t >> 3;
            const int cp = t & 7;
            const int cl  = cp ^ (r & 7);
            const ushort_t* g = qkv + (size_t)(b * SS + k0 + r) * (3 * DD) + DD + h * HD + cl * 8;
            __builtin_amdgcn_global_load_lds(
                (const __attribute__((address_space(1))) unsigned*)g,
                (__attribute__((address_space(3))) unsigned*)(Ks + (size_t)t * 8), 16, 0, 0);
            const int r2  = r + 32;
            const int cl2 = cp ^ (r2 & 7);
            const ushort_t* g2 = qkv + (size_t)(b * SS + k0 + r2) * (3 * DD) + DD + h * HD + cl2 * 8;
            __builtin_amdgcn_global_load_lds(
                (const __attribute__((address_space(1))) unsigned*)g2,
                (__attribute__((address_space(3))) unsigned*)(Ks + (size_t)(t + 256) * 8), 16, 0, 0);
        }
        // ---- stage V transposed (bf16 kpairs, swizzled) ----
        {
            const int kp = t >> 3;
            const int dg = t & 7;
            const ushort_t* g = qkv + (size_t)(b * SS + k0 + 2 * kp) * (3 * DD) + 2 * DD + h * HD + dg * 8;
            short8 va = *(const short8*)g;
            short8 vb = *(const short8*)(g + 3 * DD);
            const int kps = kp ^ ((dg & 7) * 4);
#pragma unroll
            for (int i = 0; i < 8; ++i)
                Vt2[(size_t)(dg * 8 + i) * 36 + kps] =
                    (unsigned)(ushort_t)va[i] | ((unsigned)(ushort_t)vb[i] << 16);
        }
        __syncthreads();

        // ---- S = Q K^T ----
        f32x4 sacc[4] = {};
#pragma unroll
        for (int kc = 0; kc < 2; ++kc) {
            const short8 qv = kc ? qf1 : qf0;
#pragma unroll
            for (int nt = 0; nt < 4; ++nt) {
                const int row = nt * 16 + l15;
                const int cp  = (kc * 4 + quad) ^ (row & 7);
                const short8 kf = *(const short8*)(Ks + (size_t)row * 64 + cp * 8);
                sacc[nt] = __builtin_amdgcn_mfma_f32_16x16x32_bf16(qv, kf, sacc[nt], 0, 0, 0);
            }
        }

        // ---- rel/mask + direct exp (no max, no rescale, no cross-lane) ----
#pragma unroll
        for (int reg = 0; reg < 4; ++reg) {
            const int qloc = w * 16 + quad * 4 + reg;
            const unsigned cds = codes[((size_t)(b * SS + q0 + qloc) * 16 + kt) * 16 + l15];
            const float4 r4 = r3v[reg];
#pragma unroll
            for (int nt = 0; nt < 4; ++nt) {
                const unsigned c = (cds >> (8 * nt)) & 0xff;
                float rvv = (c == 0) ? r4.x : (c == 1) ? r4.y : (c == 2) ? r4.z : r4.w;
                const float p = __expf((sacc[nt][reg] + rvv) * 0.125f);
                l_run[reg] += p;
                Ps[(size_t)qloc * 72 + nt * 16 + l15] = f2bf_rne(p);
            }
        }

        // ---- O += P V (per-wave LDS region; same-wave, no barrier) ----
#pragma unroll
        for (int kc = 0; kc < 2; ++kc) {
            const short8 pf = *(const short8*)(Ps + (size_t)(w * 16 + l15) * 72 + kc * 32 + quad * 8);
#pragma unroll
            for (int dt = 0; dt < 4; ++dt) {
                const int d  = dt * 16 + l15;
                const int dg = d >> 3;
                const int kps0 = (kc * 16 + quad * 4) ^ ((dg & 7) * 4);
                const short8 vf = *(const short8*)((const ushort_t*)&Vt2[(size_t)d * 36 + kps0]);
                oacc[dt] = __builtin_amdgcn_mfma_f32_16x16x32_bf16(pf, vf, oacc[dt], 0, 0, 0);
            }
        }
    }

    // ---- epilogue: reduce l across the 16-lane row group; emit partials ----
    float* Op = Opart + (size_t)ks * BSD;
    float* lp = lpart + (size_t)ks * BS2 * HH;
#pragma unroll
    for (int reg = 0; reg < 4; ++reg) {
        float ls = l_run[reg];
        ls += __shfl_xor(ls, 1);
        ls += __shfl_xor(ls, 2);
        ls += __shfl_xor(ls, 4);
        ls += __shfl_xor(ls, 8);
        const int orow = b * SS + q0 + w * 16 + quad * 4 + reg;
#pragma unroll
        for (int dt = 0; dt < 4; ++dt)
            Op[(size_t)orow * DD + h * HD + dt * 16 + l15] = oacc[dt][reg];
        if (l15 == 0) lp[(size_t)orow * HH + h] = ls;
    }
}

// ---------------------------------------------------------------------------
// attn_merge: att_bf = (O0 + O1) / (l0 + l1), bf16 out.
// ---------------------------------------------------------------------------
__global__ __launch_bounds__(256) void attn_merge(
    const float* __restrict__ Opart, const float* __restrict__ lpart,
    ushort_t* __restrict__ att_bf)
{
    int i = blockIdx.x * 256 + threadIdx.x;       // BS*DD/4 threads
    int row = (i * 4) / DD;
    int h   = ((i * 4) % DD) >> 6;
    float l0 = lpart[(size_t)row * HH + h];
    float l1 = lpart[(size_t)BS2 * HH + (size_t)row * HH + h];
    float inv = 1.0f / (l0 + l1);
    float4 o0 = ((const float4*)Opart)[i];
    float4 o1 = ((const float4*)(Opart + BSD))[i];
    ushort4 o;
    o.x = f2bf_rne((o0.x + o1.x) * inv);
    o.y = f2bf_rne((o0.y + o1.y) * inv);
    o.z = f2bf_rne((o0.z + o1.z) * inv);
    o.w = f2bf_rne((o0.w + o1.w) * inv);
    ((ushort4*)att_bf)[i] = o;
}

// ---------------------------------------------------------------------------
extern "C" void kernel_launch(void* const* d_in, const int* in_sizes, int n_in,
                              void* d_out, int out_size, void* d_ws, size_t ws_size,
                              hipStream_t stream) {
    const float* inp   = (const float*)d_in[0];
    const uchar_t* amask = (const uchar_t*)d_in[1];
    const int*   relm  = (const int*)d_in[2];
    const float* qkv_w = (const float*)d_in[3];
    const float* rel_A = (const float*)d_in[4];
    const float* o_w   = (const float*)d_in[5];
    const float* w1    = (const float*)d_in[6];
    const float* b1    = (const float*)d_in[7];
    const float* w2    = (const float*)d_in[8];
    const float* b2    = (const float*)d_in[9];
    const float* ln1_g = (const float*)d_in[10];
    const float* ln1_b = (const float*)d_in[11];
    const float* ln2_g = (const float*)d_in[12];
    const float* ln2_b = (const float*)d_in[13];
    float* out = (float*)d_out;

    // workspace layout
    char* p = (char*)d_ws;
    ushort_t* x_bf   = (ushort_t*)p; p += BSD * 2;
    ushort_t* att_bf = (ushort_t*)p; p += BSD * 2;
    ushort_t* h_bf   = (ushort_t*)p; p += BSD * 2;
    ushort_t* ff_bf  = (ushort_t*)p; p += (size_t)BS2 * DFF * 2;
    ushort_t* qkvw_bf= (ushort_t*)p; p += (size_t)3 * DD * DD * 2;
    ushort_t* ow_bf  = (ushort_t*)p; p += (size_t)DD * DD * 2;
    ushort_t* w1_bf  = (ushort_t*)p; p += (size_t)DFF * DD * 2;
    ushort_t* w2_bf  = (ushort_t*)p; p += (size_t)DD * DFF * 2;
    ushort_t* qkv_bf = (ushort_t*)p; p += (size_t)BS2 * 3 * DD * 2;
    float*    resid  = (float*)p;    p += BSD * 4;
    float*    Opart  = (float*)p;    p += 2 * BSD * 4;
    float*    lpart  = (float*)p;    p += (size_t)2 * BS2 * HH * 4;
    unsigned* codes  = (unsigned*)p; p += (size_t)BB * SS * SS;   // 2 MB

    // 0. weight conversions + codes + resid seed (resid = inp)
    {
        int n4;
        n4 = 3 * DD * DD / 4;
        cvt_bf16<<<(n4 + 255) / 256, 256, 0, stream>>>(qkv_w, qkvw_bf, n4);
        n4 = DD * DD / 4;
        cvt_bf16<<<(n4 + 255) / 256, 256, 0, stream>>>(o_w, ow_bf, n4);
        n4 = DFF * DD / 4;
        cvt_bf16<<<(n4 + 255) / 256, 256, 0, stream>>>(w1, w1_bf, n4);
        cvt_bf16<<<(n4 + 255) / 256, 256, 0, stream>>>(w2, w2_bf, n4);
        build_codes<<<(BB * SS * 256) / 256, 256, 0, stream>>>(relm, amask, codes);
        hipMemcpyAsync(resid, inp, BSD * 4, hipMemcpyDeviceToDevice, stream);
    }

    // 1. LN1 -> bf16
    ln_kernel_bf<<<BS2, 256, 0, stream>>>(inp, ln1_g, ln1_b, x_bf);

    // 2. QKV = x @ qkv_w.T -> bf16 : (36,32,1) x 2 waves = 2304 waves
    gemm_wave2<false, true, false, false>
        <<<dim3(3 * DD / 64, BS2 / 64, 1), 128, 0, stream>>>(
        x_bf, qkvw_bf, nullptr, qkv_bf, BS2, 3 * DD, DD, DD);

    // 3. attention, k-split x2 : grid 768
    attn_mfma_kernel<<<BB * HH * 16 * 2, 256, 0, stream>>>(
        qkv_bf, codes, rel_A, Opart, lpart);
    attn_merge<<<(int)(BSD / 4 / 256), 256, 0, stream>>>(Opart, lpart, att_bf);

    // 4. resid += att @ o_w.T : (12,32,2) x 2 waves = 1536 waves, atomic
    gemm_wave2<false, false, false, true>
        <<<dim3(DD / 64, BS2 / 64, 2), 128, 0, stream>>>(
        att_bf, ow_bf, nullptr, resid, BS2, DD, DD, DD / 2);

    // 5. LN2 -> bf16
    ln_kernel_bf<<<BS2, 256, 0, stream>>>(resid, ln2_g, ln2_b, h_bf);

    // 6. ff = relu(h @ w1.T + b1) -> bf16 : (48,32,1) x 2 = 3072 waves
    gemm_wave2<true, true, true, false>
        <<<dim3(DFF / 64, BS2 / 64, 1), 128, 0, stream>>>(
        h_bf, w1_bf, b1, ff_bf, BS2, DFF, DD, DD);

    // 7a. out = resid + b2
    init_out_kernel<<<(int)(BSD / 4 + 255) / 256, 256, 0, stream>>>(
        resid, b2, out, (int)(BSD / 4));

    // 7b. out += ff @ w2.T : (12,32,4) x 2 = 3072 waves, atomic
    gemm_wave2<false, false, false, true>
        <<<dim3(DD / 64, BS2 / 64, 4), 128, 0, stream>>>(
        ff_bf, w2_bf, nullptr, out, BS2, DD, DFF, DFF / 4);
}

// Round 7
// 278.349 us; speedup vs baseline: 1.1326x; 1.0561x over previous
//
#include <hip/hip_runtime.h>
#include <hip/hip_bf16.h>

// Problem constants
#define BB 2
#define SS 1024
#define DD 768
#define HH 12
#define HD 64
#define DFF 3072
#define EPS 1e-5f
#define BS2 (BB * SS)            // 2048
#define BSD ((size_t)BS2 * DD)   // 2048*768

typedef unsigned short ushort_t;
typedef unsigned char uchar_t;
using short8 = __attribute__((ext_vector_type(8))) short;
using f32x4  = __attribute__((ext_vector_type(4))) float;

__device__ __forceinline__ ushort_t f2bf_rne(float f) {
    union { float f; unsigned u; } x; x.f = f;
    unsigned r = x.u + 0x7fff + ((x.u >> 16) & 1);
    return (ushort_t)(r >> 16);
}
__device__ __forceinline__ float bf2f(short u) {
    union { unsigned i; float f; } x;
    x.i = ((unsigned)(ushort_t)u) << 16;
    return x.f;
}

// ---------------------------------------------------------------------------
// fp32 -> bf16 conversion (vectorized), n4 = n/4
// ---------------------------------------------------------------------------
__global__ __launch_bounds__(256) void cvt_bf16(
    const float* __restrict__ in, ushort_t* __restrict__ out, int n4)
{
    int i = blockIdx.x * 256 + threadIdx.x;
    if (i < n4) {
        float4 v = ((const float4*)in)[i];
        ushort4 o;
        o.x = f2bf_rne(v.x); o.y = f2bf_rne(v.y);
        o.z = f2bf_rne(v.z); o.w = f2bf_rne(v.w);
        ((ushort4*)out)[i] = o;
    }
}

// ---------------------------------------------------------------------------
// Pack rel+mask into lane-permuted int8 codes.
// ---------------------------------------------------------------------------
__global__ __launch_bounds__(256) void build_codes(
    const int* __restrict__ rel, const uchar_t* __restrict__ mask,
    unsigned* __restrict__ codes)
{
    int tid = blockIdx.x * 256 + threadIdx.x;      // B*S*16*16 total
    int l15 = tid & 15;
    int kt  = (tid >> 4) & 15;
    int q   = (tid >> 8) & (SS - 1);
    int b   = tid >> 18;
    const int* rrow = rel + ((size_t)(b * SS + q)) * SS + kt * 64 + l15;
    const uchar_t* mrow = mask + (size_t)b * SS + kt * 64 + l15;
    unsigned o = 0;
#pragma unroll
    for (int nt = 0; nt < 4; ++nt) {
        unsigned c = mrow[nt * 16] ? 3u : (unsigned)(rrow[nt * 16] + 1);
        o |= c << (8 * nt);
    }
    codes[((size_t)(b * SS + q) * 16 + kt) * 16 + l15] = o;
}

// ---------------------------------------------------------------------------
// LayerNorm: fp32 in -> bf16 out.
// ---------------------------------------------------------------------------
__global__ __launch_bounds__(256) void ln_kernel_bf(
    const float* __restrict__ x, const float* __restrict__ g,
    const float* __restrict__ b, ushort_t* __restrict__ y)
{
    const int row = blockIdx.x;
    const float* xr = x + (size_t)row * DD;
    float s = 0.f, ss = 0.f;
    for (int i = threadIdx.x; i < DD; i += 256) {
        float v = xr[i];
        s += v; ss += v * v;
    }
    for (int off = 32; off; off >>= 1) {
        s  += __shfl_down(s,  off);
        ss += __shfl_down(ss, off);
    }
    __shared__ float reds[4], redss[4], bc[2];
    int t = threadIdx.x;
    if ((t & 63) == 0) { reds[t >> 6] = s; redss[t >> 6] = ss; }
    __syncthreads();
    if (t == 0) {
        float S1 = reds[0] + reds[1] + reds[2] + reds[3];
        float S2 = redss[0] + redss[1] + redss[2] + redss[3];
        float mean = S1 / DD;
        float var = S2 / DD - mean * mean;
        bc[0] = mean;
        bc[1] = rsqrtf(var + EPS);
    }
    __syncthreads();
    float mean = bc[0], inv = bc[1];
    ushort_t* yr = y + (size_t)row * DD;
    for (int i = threadIdx.x; i < DD; i += 256) {
        yr[i] = f2bf_rne((xr[i] - mean) * inv * g[i] + b[i]);
    }
}

// ---------------------------------------------------------------------------
// merge_partials: outp = base (+bias) + sum_z part[z]; all fp32, float4.
// ---------------------------------------------------------------------------
template <int Z, bool HAS_BIAS>
__global__ __launch_bounds__(256) void merge_partials(
    const float* __restrict__ part, const float* __restrict__ base,
    const float* __restrict__ bias, float* __restrict__ outp, int n4)
{
    int i = blockIdx.x * 256 + threadIdx.x;
    if (i >= n4) return;
    float4 v = ((const float4*)base)[i];
    if (HAS_BIAS) {
        int col4 = (i * 4) % DD;
        float4 bv = *(const float4*)(bias + col4);
        v.x += bv.x; v.y += bv.y; v.z += bv.z; v.w += bv.w;
    }
#pragma unroll
    for (int z = 0; z < Z; ++z) {
        float4 pz = ((const float4*)(part + (size_t)z * BSD))[i];
        v.x += pz.x; v.y += pz.y; v.z += pz.z; v.w += pz.w;
    }
    ((float4*)outp)[i] = v;
}

// ---------------------------------------------------------------------------
// LDS-staged MFMA GEMM, 128x64 tile, BK=32, 256 threads = 4 waves.
// Wave w: m-off = (w&1)*64, n-off = (w>>1)*32; 4x2 sub-tiles of 16x16x32.
// LDS chunk layout (conflict-free, round-3/4 verified):
//   As slot = kq*128 + row (512 slots), Bs slot = kq*64 + row (256 slots),
//   8 bf16 per slot; staged with global_load_lds width=16 (3 instrs/iter).
// grid = (N/64, M/128, Z); Ksplit = K/Z. PARTIAL -> fp32 slice per z.
// ---------------------------------------------------------------------------
template <bool RELU, bool OUT_BF16, bool HAS_BIAS, bool PARTIAL>
__global__ __launch_bounds__(256) void gemm_tile(
    const ushort_t* __restrict__ A, const ushort_t* __restrict__ W,
    const float* __restrict__ bias, void* __restrict__ Cout,
    int M, int N, int K, int Ksplit)
{
    __shared__ __align__(16) ushort_t As[512 * 8];   // 8 KB
    __shared__ __align__(16) ushort_t Bs[256 * 8];   // 4 KB

    const int t  = threadIdx.x;
    const int n0 = blockIdx.x * 64;
    const int m0 = blockIdx.y * 128;
    const int kb = blockIdx.z * Ksplit;
    const int w  = t >> 6;
    const int l  = t & 63;
    const int wm = (w & 1) * 64;
    const int wn = (w >> 1) * 32;
    const int l15  = l & 15;
    const int quad = l >> 4;

    const ushort_t* gA0 = A + (size_t)(m0 + (t & 127)) * K + kb + (t >> 7) * 8;
    const ushort_t* gA1 = gA0 + 16;
    const ushort_t* gB0 = W + (size_t)(n0 + (t & 63)) * K + kb + (t >> 6) * 8;
    ushort_t* lA0 = &As[(size_t)t * 8];
    ushort_t* lA1 = &As[(size_t)(t + 256) * 8];
    ushort_t* lB0 = &Bs[(size_t)t * 8];

    const ushort_t* aptr = &As[(size_t)(quad * 128 + wm + l15) * 8];
    const ushort_t* bptr = &Bs[(size_t)(quad * 64 + wn + l15) * 8];

    f32x4 acc[4][2] = {};

    for (int k0 = 0; k0 < Ksplit; k0 += 32) {
        __syncthreads();
        __builtin_amdgcn_global_load_lds(
            (const __attribute__((address_space(1))) unsigned int*)(gA0 + k0),
            (__attribute__((address_space(3))) unsigned int*)lA0, 16, 0, 0);
        __builtin_amdgcn_global_load_lds(
            (const __attribute__((address_space(1))) unsigned int*)(gA1 + k0),
            (__attribute__((address_space(3))) unsigned int*)lA1, 16, 0, 0);
        __builtin_amdgcn_global_load_lds(
            (const __attribute__((address_space(1))) unsigned int*)(gB0 + k0),
            (__attribute__((address_space(3))) unsigned int*)lB0, 16, 0, 0);
        __syncthreads();

        short8 af[4], bf[2];
#pragma unroll
        for (int i = 0; i < 4; ++i)
            af[i] = *(const short8*)(aptr + (size_t)i * 16 * 8);
#pragma unroll
        for (int j = 0; j < 2; ++j)
            bf[j] = *(const short8*)(bptr + (size_t)j * 16 * 8);
#pragma unroll
        for (int i = 0; i < 4; ++i)
#pragma unroll
            for (int j = 0; j < 2; ++j)
                acc[i][j] = __builtin_amdgcn_mfma_f32_16x16x32_bf16(
                    af[i], bf[j], acc[i][j], 0, 0, 0);
    }

    // epilogue: C/D layout col=lane&15, row=(lane>>4)*4+reg
    if (PARTIAL) {
        float* Cp = (float*)Cout + (size_t)blockIdx.z * ((size_t)M * N);
#pragma unroll
        for (int i = 0; i < 4; ++i) {
            const int row = m0 + wm + i * 16 + quad * 4;
#pragma unroll
            for (int j = 0; j < 2; ++j) {
                const int col = n0 + wn + j * 16 + l15;
#pragma unroll
                for (int r = 0; r < 4; ++r)
                    Cp[(size_t)(row + r) * N + col] = acc[i][j][r];
            }
        }
    } else {
#pragma unroll
        for (int i = 0; i < 4; ++i) {
            const int row = m0 + wm + i * 16 + quad * 4;
#pragma unroll
            for (int j = 0; j < 2; ++j) {
                const int col = n0 + wn + j * 16 + l15;
                const float bv = HAS_BIAS ? bias[col] : 0.f;
#pragma unroll
                for (int r = 0; r < 4; ++r) {
                    float v = acc[i][j][r] + bv;
                    if (RELU) v = fmaxf(v, 0.f);
                    if (OUT_BF16)
                        ((ushort_t*)Cout)[(size_t)(row + r) * N + col] = f2bf_rne(v);
                    else
                        ((float*)Cout)[(size_t)(row + r) * N + col] = v;
                }
            }
        }
    }
}

// ---------------------------------------------------------------------------
// MFMA flash attention, K-SPLIT x4, direct exp (no online max: logits are
// small; masked entries hit -2.4e31 sentinel -> exp = 0). No cross-lane ops
// in the k-loop. Emits unnormalized O (fp32) + l partials per split slice.
// Block per (b, h, qtile, ks): grid = 2*12*16*4 = 1536.
// ---------------------------------------------------------------------------
__global__ __launch_bounds__(256) void attn_mfma_kernel(
    const ushort_t* __restrict__ qkv,      // (B*S, 2304) bf16
    const unsigned* __restrict__ codes,    // packed rel/mask codes
    const float* __restrict__ rel_A,       // (3, 64) fp32
    float* __restrict__ Opart,             // [4][BS*DD] fp32 unnormalized
    float* __restrict__ lpart)             // [4][BS*HH] fp32 row sums
{
    __shared__ __align__(16) ushort_t Ks[64 * 64];
    __shared__ __align__(16) unsigned Vt2[64 * 36];
    __shared__ __align__(16) ushort_t Ps[64 * 72];
    __shared__ __align__(16) float r3s[64][4];

    const int bx = blockIdx.x;
    const int ks = bx & 3;
    const int qt = (bx >> 2) & 15;
    const int h  = (bx >> 6) % HH;
    const int b  = bx / (64 * HH);
    const int q0 = qt * 64;
    const int t  = threadIdx.x;
    const int w  = t >> 6;
    const int l  = t & 63;
    const int l15  = l & 15;
    const int quad = l >> 4;

    const size_t qrow = (size_t)(b * SS + q0 + w * 16 + l15) * (3 * DD) + h * HD;
    const short8 qf0 = *(const short8*)(qkv + qrow + quad * 8);
    const short8 qf1 = *(const short8*)(qkv + qrow + 32 + quad * 8);

    {
        float rv[3];
#pragma unroll
        for (int c = 0; c < 3; ++c) {
            const float* a = rel_A + c * HD + quad * 8;
            float acc = 0.f;
#pragma unroll
            for (int j = 0; j < 8; ++j) acc += bf2f(qf0[j]) * a[j];
#pragma unroll
            for (int j = 0; j < 8; ++j) acc += bf2f(qf1[j]) * a[32 + j];
            acc += __shfl_xor(acc, 16);
            acc += __shfl_xor(acc, 32);
            rv[c] = acc;
        }
        if (quad == 0) {
            float4 f4 = make_float4(rv[0], rv[1], rv[2], -2.4e31f);
            *(float4*)&r3s[w * 16 + l15][0] = f4;
        }
    }
    __syncthreads();
    float4 r3v[4];
#pragma unroll
    for (int reg = 0; reg < 4; ++reg)
        r3v[reg] = *(const float4*)&r3s[w * 16 + quad * 4 + reg][0];

    float l_run[4] = {0.f, 0.f, 0.f, 0.f};
    f32x4 oacc[4] = {};

    for (int kt = ks * 4; kt < ks * 4 + 4; ++kt) {
        const int k0 = kt * 64;
        __syncthreads();
        // ---- stage K (XOR-swizzled chunks) ----
        {
            const int r  = t >> 3;
            const int cp = t & 7;
            const int cl  = cp ^ (r & 7);
            const ushort_t* g = qkv + (size_t)(b * SS + k0 + r) * (3 * DD) + DD + h * HD + cl * 8;
            __builtin_amdgcn_global_load_lds(
                (const __attribute__((address_space(1))) unsigned*)g,
                (__attribute__((address_space(3))) unsigned*)(Ks + (size_t)t * 8), 16, 0, 0);
            const int r2  = r + 32;
            const int cl2 = cp ^ (r2 & 7);
            const ushort_t* g2 = qkv + (size_t)(b * SS + k0 + r2) * (3 * DD) + DD + h * HD + cl2 * 8;
            __builtin_amdgcn_global_load_lds(
                (const __attribute__((address_space(1))) unsigned*)g2,
                (__attribute__((address_space(3))) unsigned*)(Ks + (size_t)(t + 256) * 8), 16, 0, 0);
        }
        // ---- stage V transposed (bf16 kpairs, swizzled) ----
        {
            const int kp = t >> 3;
            const int dg = t & 7;
            const ushort_t* g = qkv + (size_t)(b * SS + k0 + 2 * kp) * (3 * DD) + 2 * DD + h * HD + dg * 8;
            short8 va = *(const short8*)g;
            short8 vb = *(const short8*)(g + 3 * DD);
            const int kps = kp ^ ((dg & 7) * 4);
#pragma unroll
            for (int i = 0; i < 8; ++i)
                Vt2[(size_t)(dg * 8 + i) * 36 + kps] =
                    (unsigned)(ushort_t)va[i] | ((unsigned)(ushort_t)vb[i] << 16);
        }
        __syncthreads();

        // ---- S = Q K^T ----
        f32x4 sacc[4] = {};
#pragma unroll
        for (int kc = 0; kc < 2; ++kc) {
            const short8 qv = kc ? qf1 : qf0;
#pragma unroll
            for (int nt = 0; nt < 4; ++nt) {
                const int row = nt * 16 + l15;
                const int cp  = (kc * 4 + quad) ^ (row & 7);
                const short8 kf = *(const short8*)(Ks + (size_t)row * 64 + cp * 8);
                sacc[nt] = __builtin_amdgcn_mfma_f32_16x16x32_bf16(qv, kf, sacc[nt], 0, 0, 0);
            }
        }

        // ---- rel/mask + direct exp ----
#pragma unroll
        for (int reg = 0; reg < 4; ++reg) {
            const int qloc = w * 16 + quad * 4 + reg;
            const unsigned cds = codes[((size_t)(b * SS + q0 + qloc) * 16 + kt) * 16 + l15];
            const float4 r4 = r3v[reg];
#pragma unroll
            for (int nt = 0; nt < 4; ++nt) {
                const unsigned c = (cds >> (8 * nt)) & 0xff;
                float rvv = (c == 0) ? r4.x : (c == 1) ? r4.y : (c == 2) ? r4.z : r4.w;
                const float p = __expf((sacc[nt][reg] + rvv) * 0.125f);
                l_run[reg] += p;
                Ps[(size_t)qloc * 72 + nt * 16 + l15] = f2bf_rne(p);
            }
        }

        // ---- O += P V (per-wave LDS region; same-wave, no barrier) ----
#pragma unroll
        for (int kc = 0; kc < 2; ++kc) {
            const short8 pf = *(const short8*)(Ps + (size_t)(w * 16 + l15) * 72 + kc * 32 + quad * 8);
#pragma unroll
            for (int dt = 0; dt < 4; ++dt) {
                const int d  = dt * 16 + l15;
                const int dg = d >> 3;
                const int kps0 = (kc * 16 + quad * 4) ^ ((dg & 7) * 4);
                const short8 vf = *(const short8*)((const ushort_t*)&Vt2[(size_t)d * 36 + kps0]);
                oacc[dt] = __builtin_amdgcn_mfma_f32_16x16x32_bf16(pf, vf, oacc[dt], 0, 0, 0);
            }
        }
    }

    // ---- epilogue: reduce l across the 16-lane row group; emit partials ----
    float* Op = Opart + (size_t)ks * BSD;
    float* lp = lpart + (size_t)ks * BS2 * HH;
#pragma unroll
    for (int reg = 0; reg < 4; ++reg) {
        float ls = l_run[reg];
        ls += __shfl_xor(ls, 1);
        ls += __shfl_xor(ls, 2);
        ls += __shfl_xor(ls, 4);
        ls += __shfl_xor(ls, 8);
        const int orow = b * SS + q0 + w * 16 + quad * 4 + reg;
#pragma unroll
        for (int dt = 0; dt < 4; ++dt)
            Op[(size_t)orow * DD + h * HD + dt * 16 + l15] = oacc[dt][reg];
        if (l15 == 0) lp[(size_t)orow * HH + h] = ls;
    }
}

// ---------------------------------------------------------------------------
// attn_merge: att_bf = (O0+O1+O2+O3) / (l0+l1+l2+l3), bf16 out.
// ---------------------------------------------------------------------------
__global__ __launch_bounds__(256) void attn_merge(
    const float* __restrict__ Opart, const float* __restrict__ lpart,
    ushort_t* __restrict__ att_bf)
{
    int i = blockIdx.x * 256 + threadIdx.x;       // BS*DD/4 threads
    int row = (i * 4) / DD;
    int h   = ((i * 4) % DD) >> 6;
    float lsum = 0.f;
#pragma unroll
    for (int z = 0; z < 4; ++z)
        lsum += lpart[(size_t)z * BS2 * HH + (size_t)row * HH + h];
    float inv = 1.0f / lsum;
    float4 os = ((const float4*)Opart)[i];
#pragma unroll
    for (int z = 1; z < 4; ++z) {
        float4 oz = ((const float4*)(Opart + (size_t)z * BSD))[i];
        os.x += oz.x; os.y += oz.y; os.z += oz.z; os.w += oz.w;
    }
    ushort4 o;
    o.x = f2bf_rne(os.x * inv);
    o.y = f2bf_rne(os.y * inv);
    o.z = f2bf_rne(os.z * inv);
    o.w = f2bf_rne(os.w * inv);
    ((ushort4*)att_bf)[i] = o;
}

// ---------------------------------------------------------------------------
extern "C" void kernel_launch(void* const* d_in, const int* in_sizes, int n_in,
                              void* d_out, int out_size, void* d_ws, size_t ws_size,
                              hipStream_t stream) {
    const float* inp   = (const float*)d_in[0];
    const uchar_t* amask = (const uchar_t*)d_in[1];
    const int*   relm  = (const int*)d_in[2];
    const float* qkv_w = (const float*)d_in[3];
    const float* rel_A = (const float*)d_in[4];
    const float* o_w   = (const float*)d_in[5];
    const float* w1    = (const float*)d_in[6];
    const float* b1    = (const float*)d_in[7];
    const float* w2    = (const float*)d_in[8];
    const float* b2    = (const float*)d_in[9];
    const float* ln1_g = (const float*)d_in[10];
    const float* ln1_b = (const float*)d_in[11];
    const float* ln2_g = (const float*)d_in[12];
    const float* ln2_b = (const float*)d_in[13];
    float* out = (float*)d_out;

    // workspace layout
    char* p = (char*)d_ws;
    ushort_t* x_bf   = (ushort_t*)p; p += BSD * 2;
    ushort_t* att_bf = (ushort_t*)p; p += BSD * 2;
    ushort_t* h_bf   = (ushort_t*)p; p += BSD * 2;
    ushort_t* ff_bf  = (ushort_t*)p; p += (size_t)BS2 * DFF * 2;
    ushort_t* qkvw_bf= (ushort_t*)p; p += (size_t)3 * DD * DD * 2;
    ushort_t* ow_bf  = (ushort_t*)p; p += (size_t)DD * DD * 2;
    ushort_t* w1_bf  = (ushort_t*)p; p += (size_t)DFF * DD * 2;
    ushort_t* w2_bf  = (ushort_t*)p; p += (size_t)DD * DFF * 2;
    ushort_t* qkv_bf = (ushort_t*)p; p += (size_t)BS2 * 3 * DD * 2;
    float*    resid  = (float*)p;    p += BSD * 4;
    float*    pool   = (float*)p;    p += 4 * BSD * 4;   // shared partial pool (25 MB)
    float*    lpart  = (float*)p;    p += (size_t)4 * BS2 * HH * 4;
    unsigned* codes  = (unsigned*)p; p += (size_t)BB * SS * SS;   // 2 MB

    // 0. weight conversions + codes
    {
        int n4;
        n4 = 3 * DD * DD / 4;
        cvt_bf16<<<(n4 + 255) / 256, 256, 0, stream>>>(qkv_w, qkvw_bf, n4);
        n4 = DD * DD / 4;
        cvt_bf16<<<(n4 + 255) / 256, 256, 0, stream>>>(o_w, ow_bf, n4);
        n4 = DFF * DD / 4;
        cvt_bf16<<<(n4 + 255) / 256, 256, 0, stream>>>(w1, w1_bf, n4);
        cvt_bf16<<<(n4 + 255) / 256, 256, 0, stream>>>(w2, w2_bf, n4);
        build_codes<<<(BB * SS * 256) / 256, 256, 0, stream>>>(relm, amask, codes);
    }

    // 1. LN1 -> bf16
    ln_kernel_bf<<<BS2, 256, 0, stream>>>(inp, ln1_g, ln1_b, x_bf);

    // 2. QKV = x @ qkv_w.T -> bf16 : grid (36,16) = 576 blocks, no split
    gemm_tile<false, true, false, false>
        <<<dim3(3 * DD / 64, BS2 / 128, 1), 256, 0, stream>>>(
        x_bf, qkvw_bf, nullptr, qkv_bf, BS2, 3 * DD, DD, DD);

    // 3. attention, k-split x4 : grid 1536 ; merge -> bf16
    attn_mfma_kernel<<<BB * HH * 16 * 4, 256, 0, stream>>>(
        qkv_bf, codes, rel_A, pool, lpart);
    attn_merge<<<(int)(BSD / 4 / 256), 256, 0, stream>>>(pool, lpart, att_bf);

    // 4. o-proj partials (Z=2) : grid (12,16,2) = 384 blocks
    gemm_tile<false, false, false, true>
        <<<dim3(DD / 64, BS2 / 128, 2), 256, 0, stream>>>(
        att_bf, ow_bf, nullptr, pool, BS2, DD, DD, DD / 2);
    //    resid = inp + p0 + p1
    merge_partials<2, false><<<(int)(BSD / 4 / 256), 256, 0, stream>>>(
        pool, inp, nullptr, resid, (int)(BSD / 4));

    // 5. LN2 -> bf16
    ln_kernel_bf<<<BS2, 256, 0, stream>>>(resid, ln2_g, ln2_b, h_bf);

    // 6. ff = relu(h @ w1.T + b1) -> bf16 : grid (48,16) = 768 blocks
    gemm_tile<true, true, true, false>
        <<<dim3(DFF / 64, BS2 / 128, 1), 256, 0, stream>>>(
        h_bf, w1_bf, b1, ff_bf, BS2, DFF, DD, DD);

    // 7. MLP2 partials (Z=4) : grid (12,16,4) = 768 blocks
    gemm_tile<false, false, false, true>
        <<<dim3(DD / 64, BS2 / 128, 4), 256, 0, stream>>>(
        ff_bf, w2_bf, nullptr, pool, BS2, DD, DFF, DFF / 4);
    //    out = resid + b2 + p0 + p1 + p2 + p3
    merge_partials<4, true><<<(int)(BSD / 4 / 256), 256, 0, stream>>>(
        pool, resid, b2, out, (int)(BSD / 4));
}

// Round 8
// 275.298 us; speedup vs baseline: 1.1451x; 1.0111x over previous
//
#include <hip/hip_runtime.h>
#include <hip/hip_bf16.h>

// Problem constants
#define BB 2
#define SS 1024
#define DD 768
#define HH 12
#define HD 64
#define DFF 3072
#define EPS 1e-5f
#define BS2 (BB * SS)            // 2048
#define BSD ((size_t)BS2 * DD)   // 2048*768

typedef unsigned short ushort_t;
typedef unsigned char uchar_t;
using short8 = __attribute__((ext_vector_type(8))) short;
using f32x4  = __attribute__((ext_vector_type(4))) float;

__device__ __forceinline__ ushort_t f2bf_rne(float f) {
    union { float f; unsigned u; } x; x.f = f;
    unsigned r = x.u + 0x7fff + ((x.u >> 16) & 1);
    return (ushort_t)(r >> 16);
}
__device__ __forceinline__ float bf2f(short u) {
    union { unsigned i; float f; } x;
    x.i = ((unsigned)(ushort_t)u) << 16;
    return x.f;
}

// ---------------------------------------------------------------------------
// cvt_all: convert all four weight matrices fp32->bf16 in ONE launch.
// Destination bf16 buffers are contiguous in ws in this order.
// ---------------------------------------------------------------------------
#define CVT_N1 (3 * DD * DD / 4)
#define CVT_N2 (CVT_N1 + DD * DD / 4)
#define CVT_N3 (CVT_N2 + DFF * DD / 4)
#define CVT_NT (CVT_N3 + DD * DFF / 4)

__global__ __launch_bounds__(256) void cvt_all(
    const float* __restrict__ qkv_w, const float* __restrict__ o_w,
    const float* __restrict__ w1, const float* __restrict__ w2,
    ushort_t* __restrict__ dst)
{
    int i = blockIdx.x * 256 + threadIdx.x;
    if (i >= CVT_NT) return;
    const float* src; int off;
    if (i < CVT_N1)      { src = qkv_w; off = i; }
    else if (i < CVT_N2) { src = o_w;   off = i - CVT_N1; }
    else if (i < CVT_N3) { src = w1;    off = i - CVT_N2; }
    else                 { src = w2;    off = i - CVT_N3; }
    float4 v = ((const float4*)src)[off];
    ushort4 o;
    o.x = f2bf_rne(v.x); o.y = f2bf_rne(v.y);
    o.z = f2bf_rne(v.z); o.w = f2bf_rne(v.w);
    ((ushort4*)dst)[i] = o;
}

// ---------------------------------------------------------------------------
// Pack rel+mask into lane-permuted int8 codes.
// ---------------------------------------------------------------------------
__global__ __launch_bounds__(256) void build_codes(
    const int* __restrict__ rel, const uchar_t* __restrict__ mask,
    unsigned* __restrict__ codes)
{
    int tid = blockIdx.x * 256 + threadIdx.x;      // B*S*16*16 total
    int l15 = tid & 15;
    int kt  = (tid >> 4) & 15;
    int q   = (tid >> 8) & (SS - 1);
    int b   = tid >> 18;
    const int* rrow = rel + ((size_t)(b * SS + q)) * SS + kt * 64 + l15;
    const uchar_t* mrow = mask + (size_t)b * SS + kt * 64 + l15;
    unsigned o = 0;
#pragma unroll
    for (int nt = 0; nt < 4; ++nt) {
        unsigned c = mrow[nt * 16] ? 3u : (unsigned)(rrow[nt * 16] + 1);
        o |= c << (8 * nt);
    }
    codes[((size_t)(b * SS + q) * 16 + kt) * 16 + l15] = o;
}

// ---------------------------------------------------------------------------
// LayerNorm: fp32 in -> bf16 out (used for LN1).
// ---------------------------------------------------------------------------
__global__ __launch_bounds__(256) void ln_kernel_bf(
    const float* __restrict__ x, const float* __restrict__ g,
    const float* __restrict__ b, ushort_t* __restrict__ y)
{
    const int row = blockIdx.x;
    const float* xr = x + (size_t)row * DD;
    float s = 0.f, ss = 0.f;
    for (int i = threadIdx.x; i < DD; i += 256) {
        float v = xr[i];
        s += v; ss += v * v;
    }
    for (int off = 32; off; off >>= 1) {
        s  += __shfl_down(s,  off);
        ss += __shfl_down(ss, off);
    }
    __shared__ float reds[4], redss[4], bc[2];
    int t = threadIdx.x;
    if ((t & 63) == 0) { reds[t >> 6] = s; redss[t >> 6] = ss; }
    __syncthreads();
    if (t == 0) {
        float S1 = reds[0] + reds[1] + reds[2] + reds[3];
        float S2 = redss[0] + redss[1] + redss[2] + redss[3];
        float mean = S1 / DD;
        float var = S2 / DD - mean * mean;
        bc[0] = mean;
        bc[1] = rsqrtf(var + EPS);
    }
    __syncthreads();
    float mean = bc[0], inv = bc[1];
    ushort_t* yr = y + (size_t)row * DD;
    for (int i = threadIdx.x; i < DD; i += 256) {
        yr[i] = f2bf_rne((xr[i] - mean) * inv * g[i] + b[i]);
    }
}

// ---------------------------------------------------------------------------
// Fused: resid = inp + p0 + p1 ; h_bf = LN(resid). One block per row.
// Threads 0..191 each own one float4 of the 768-col row.
// ---------------------------------------------------------------------------
__global__ __launch_bounds__(256) void merge2_ln_kernel(
    const float* __restrict__ part, const float* __restrict__ inp,
    const float* __restrict__ g, const float* __restrict__ b,
    float* __restrict__ resid, ushort_t* __restrict__ h_bf)
{
    const int row = blockIdx.x;
    const int t = threadIdx.x;
    float4 v = make_float4(0.f, 0.f, 0.f, 0.f);
    const size_t idx = (size_t)row * (DD / 4) + t;
    if (t < DD / 4) {
        v = ((const float4*)inp)[idx];
        float4 p0 = ((const float4*)part)[idx];
        float4 p1 = ((const float4*)(part + BSD))[idx];
        v.x += p0.x + p1.x; v.y += p0.y + p1.y;
        v.z += p0.z + p1.z; v.w += p0.w + p1.w;
        ((float4*)resid)[idx] = v;
    }
    float s  = v.x + v.y + v.z + v.w;
    float ss = v.x * v.x + v.y * v.y + v.z * v.z + v.w * v.w;
    for (int off = 32; off; off >>= 1) {
        s  += __shfl_down(s,  off);
        ss += __shfl_down(ss, off);
    }
    __shared__ float reds[4], redss[4], bc[2];
    if ((t & 63) == 0) { reds[t >> 6] = s; redss[t >> 6] = ss; }
    __syncthreads();
    if (t == 0) {
        float S1 = reds[0] + reds[1] + reds[2] + reds[3];
        float S2 = redss[0] + redss[1] + redss[2] + redss[3];
        float mean = S1 / DD;
        float var = S2 / DD - mean * mean;
        bc[0] = mean;
        bc[1] = rsqrtf(var + EPS);
    }
    __syncthreads();
    if (t < DD / 4) {
        const float mean = bc[0], inv = bc[1];
        float4 gv = ((const float4*)g)[t];
        float4 bv = ((const float4*)b)[t];
        ushort4 o;
        o.x = f2bf_rne((v.x - mean) * inv * gv.x + bv.x);
        o.y = f2bf_rne((v.y - mean) * inv * gv.y + bv.y);
        o.z = f2bf_rne((v.z - mean) * inv * gv.z + bv.z);
        o.w = f2bf_rne((v.w - mean) * inv * gv.w + bv.w);
        ((ushort4*)h_bf)[idx] = o;
    }
}

// ---------------------------------------------------------------------------
// merge4: out = resid + b2 + sum of 4 partial slices.
// ---------------------------------------------------------------------------
__global__ __launch_bounds__(256) void merge4_kernel(
    const float* __restrict__ part, const float* __restrict__ resid,
    const float* __restrict__ b2, float* __restrict__ outp, int n4)
{
    int i = blockIdx.x * 256 + threadIdx.x;
    if (i >= n4) return;
    float4 v = ((const float4*)resid)[i];
    int col4 = (i * 4) % DD;
    float4 bv = *(const float4*)(b2 + col4);
    v.x += bv.x; v.y += bv.y; v.z += bv.z; v.w += bv.w;
#pragma unroll
    for (int z = 0; z < 4; ++z) {
        float4 pz = ((const float4*)(part + (size_t)z * BSD))[i];
        v.x += pz.x; v.y += pz.y; v.z += pz.z; v.w += pz.w;
    }
    ((float4*)outp)[i] = v;
}

// ---------------------------------------------------------------------------
// LDS-staged MFMA GEMM, 128x64 tile, BK=64, 256 threads = 4 waves.
// Wave w: m-off = (w&1)*64, n-off = (w>>1)*32; 4x2 sub-tiles of 16x16x32,
// two k-steps per iteration (16 MFMA/wave between barriers).
// LDS chunk layout: As slot = kq*128+row (kq 0..7), Bs slot = kq*64+row.
// grid = (N/64, M/128, Z); Ksplit = K/Z (divisible by 64).
// ---------------------------------------------------------------------------
template <bool RELU, bool OUT_BF16, bool HAS_BIAS, bool PARTIAL>
__global__ __launch_bounds__(256) void gemm_tile(
    const ushort_t* __restrict__ A, const ushort_t* __restrict__ W,
    const float* __restrict__ bias, void* __restrict__ Cout,
    int M, int N, int K, int Ksplit)
{
    __shared__ __align__(16) ushort_t As[1024 * 8];   // 16 KB
    __shared__ __align__(16) ushort_t Bs[512 * 8];    // 8 KB

    const int t  = threadIdx.x;
    const int n0 = blockIdx.x * 64;
    const int m0 = blockIdx.y * 128;
    const int kb = blockIdx.z * Ksplit;
    const int w  = t >> 6;
    const int l  = t & 63;
    const int wm = (w & 1) * 64;
    const int wn = (w >> 1) * 32;
    const int l15  = l & 15;
    const int quad = l >> 4;

    // A staging: slot t+256*ii has kq = (t>>7) + 2*ii, row = t&127
    const ushort_t* gA = A + (size_t)(m0 + (t & 127)) * K + kb + (t >> 7) * 8;
    ushort_t* lA = &As[(size_t)t * 8];
    // B staging: slot t+256*ii has kq = (t>>6) + 4*ii, row = t&63
    const ushort_t* gB = W + (size_t)(n0 + (t & 63)) * K + kb + (t >> 6) * 8;
    ushort_t* lB = &Bs[(size_t)t * 8];

    f32x4 acc[4][2] = {};

    for (int k0 = 0; k0 < Ksplit; k0 += 64) {
        __syncthreads();
#pragma unroll
        for (int ii = 0; ii < 4; ++ii)
            __builtin_amdgcn_global_load_lds(
                (const __attribute__((address_space(1))) unsigned int*)(gA + k0 + ii * 16),
                (__attribute__((address_space(3))) unsigned int*)(lA + (size_t)ii * 256 * 8),
                16, 0, 0);
#pragma unroll
        for (int ii = 0; ii < 2; ++ii)
            __builtin_amdgcn_global_load_lds(
                (const __attribute__((address_space(1))) unsigned int*)(gB + k0 + ii * 32),
                (__attribute__((address_space(3))) unsigned int*)(lB + (size_t)ii * 256 * 8),
                16, 0, 0);
        __syncthreads();

#pragma unroll
        for (int ks = 0; ks < 2; ++ks) {
            const ushort_t* aptr = &As[(size_t)((ks * 4 + quad) * 128 + wm + l15) * 8];
            const ushort_t* bptr = &Bs[(size_t)((ks * 4 + quad) * 64 + wn + l15) * 8];
            short8 af[4], bf[2];
#pragma unroll
            for (int i = 0; i < 4; ++i)
                af[i] = *(const short8*)(aptr + (size_t)i * 16 * 8);
#pragma unroll
            for (int j = 0; j < 2; ++j)
                bf[j] = *(const short8*)(bptr + (size_t)j * 16 * 8);
#pragma unroll
            for (int i = 0; i < 4; ++i)
#pragma unroll
                for (int j = 0; j < 2; ++j)
                    acc[i][j] = __builtin_amdgcn_mfma_f32_16x16x32_bf16(
                        af[i], bf[j], acc[i][j], 0, 0, 0);
        }
    }

    // epilogue: C/D layout col=lane&15, row=(lane>>4)*4+reg
    if (PARTIAL) {
        float* Cp = (float*)Cout + (size_t)blockIdx.z * ((size_t)M * N);
#pragma unroll
        for (int i = 0; i < 4; ++i) {
            const int row = m0 + wm + i * 16 + quad * 4;
#pragma unroll
            for (int j = 0; j < 2; ++j) {
                const int col = n0 + wn + j * 16 + l15;
#pragma unroll
                for (int r = 0; r < 4; ++r)
                    Cp[(size_t)(row + r) * N + col] = acc[i][j][r];
            }
        }
    } else {
#pragma unroll
        for (int i = 0; i < 4; ++i) {
            const int row = m0 + wm + i * 16 + quad * 4;
#pragma unroll
            for (int j = 0; j < 2; ++j) {
                const int col = n0 + wn + j * 16 + l15;
                const float bv = HAS_BIAS ? bias[col] : 0.f;
#pragma unroll
                for (int r = 0; r < 4; ++r) {
                    float v = acc[i][j][r] + bv;
                    if (RELU) v = fmaxf(v, 0.f);
                    if (OUT_BF16)
                        ((ushort_t*)Cout)[(size_t)(row + r) * N + col] = f2bf_rne(v);
                    else
                        ((float*)Cout)[(size_t)(row + r) * N + col] = v;
                }
            }
        }
    }
}

// ---------------------------------------------------------------------------
// MFMA flash attention, K-SPLIT x4, direct exp (no online max: logits are
// small; masked entries hit -2.4e31 sentinel -> exp = 0).
// Block per (b, h, qtile, ks): grid = 2*12*16*4 = 1536.
// ---------------------------------------------------------------------------
__global__ __launch_bounds__(256) void attn_mfma_kernel(
    const ushort_t* __restrict__ qkv,      // (B*S, 2304) bf16
    const unsigned* __restrict__ codes,    // packed rel/mask codes
    const float* __restrict__ rel_A,       // (3, 64) fp32
    float* __restrict__ Opart,             // [4][BS*DD] fp32 unnormalized
    float* __restrict__ lpart)             // [4][BS*HH] fp32 row sums
{
    __shared__ __align__(16) ushort_t Ks[64 * 64];
    __shared__ __align__(16) unsigned Vt2[64 * 36];
    __shared__ __align__(16) ushort_t Ps[64 * 72];
    __shared__ __align__(16) float r3s[64][4];

    const int bx = blockIdx.x;
    const int ks = bx & 3;
    const int qt = (bx >> 2) & 15;
    const int h  = (bx >> 6) % HH;
    const int b  = bx / (64 * HH);
    const int q0 = qt * 64;
    const int t  = threadIdx.x;
    const int w  = t >> 6;
    const int l  = t & 63;
    const int l15  = l & 15;
    const int quad = l >> 4;

    const size_t qrow = (size_t)(b * SS + q0 + w * 16 + l15) * (3 * DD) + h * HD;
    const short8 qf0 = *(const short8*)(qkv + qrow + quad * 8);
    const short8 qf1 = *(const short8*)(qkv + qrow + 32 + quad * 8);

    {
        float rv[3];
#pragma unroll
        for (int c = 0; c < 3; ++c) {
            const float* a = rel_A + c * HD + quad * 8;
            float acc = 0.f;
#pragma unroll
            for (int j = 0; j < 8; ++j) acc += bf2f(qf0[j]) * a[j];
#pragma unroll
            for (int j = 0; j < 8; ++j) acc += bf2f(qf1[j]) * a[32 + j];
            acc += __shfl_xor(acc, 16);
            acc += __shfl_xor(acc, 32);
            rv[c] = acc;
        }
        if (quad == 0) {
            float4 f4 = make_float4(rv[0], rv[1], rv[2], -2.4e31f);
            *(float4*)&r3s[w * 16 + l15][0] = f4;
        }
    }
    __syncthreads();
    float4 r3v[4];
#pragma unroll
    for (int reg = 0; reg < 4; ++reg)
        r3v[reg] = *(const float4*)&r3s[w * 16 + quad * 4 + reg][0];

    float l_run[4] = {0.f, 0.f, 0.f, 0.f};
    f32x4 oacc[4] = {};

    for (int kt = ks * 4; kt < ks * 4 + 4; ++kt) {
        const int k0 = kt * 64;
        __syncthreads();
        // ---- stage K (XOR-swizzled chunks) ----
        {
            const int r  = t >> 3;
            const int cp = t & 7;
            const int cl  = cp ^ (r & 7);
            const ushort_t* g = qkv + (size_t)(b * SS + k0 + r) * (3 * DD) + DD + h * HD + cl * 8;
            __builtin_amdgcn_global_load_lds(
                (const __attribute__((address_space(1))) unsigned*)g,
                (__attribute__((address_space(3))) unsigned*)(Ks + (size_t)t * 8), 16, 0, 0);
            const int r2  = r + 32;
            const int cl2 = cp ^ (r2 & 7);
            const ushort_t* g2 = qkv + (size_t)(b * SS + k0 + r2) * (3 * DD) + DD + h * HD + cl2 * 8;
            __builtin_amdgcn_global_load_lds(
                (const __attribute__((address_space(1))) unsigned*)g2,
                (__attribute__((address_space(3))) unsigned*)(Ks + (size_t)(t + 256) * 8), 16, 0, 0);
        }
        // ---- stage V transposed (bf16 kpairs, swizzled) ----
        {
            const int kp = t >> 3;
            const int dg = t & 7;
            const ushort_t* g = qkv + (size_t)(b * SS + k0 + 2 * kp) * (3 * DD) + 2 * DD + h * HD + dg * 8;
            short8 va = *(const short8*)g;
            short8 vb = *(const short8*)(g + 3 * DD);
            const int kps = kp ^ ((dg & 7) * 4);
#pragma unroll
            for (int i = 0; i < 8; ++i)
                Vt2[(size_t)(dg * 8 + i) * 36 + kps] =
                    (unsigned)(ushort_t)va[i] | ((unsigned)(ushort_t)vb[i] << 16);
        }
        __syncthreads();

        // ---- S = Q K^T ----
        f32x4 sacc[4] = {};
#pragma unroll
        for (int kc = 0; kc < 2; ++kc) {
            const short8 qv = kc ? qf1 : qf0;
#pragma unroll
            for (int nt = 0; nt < 4; ++nt) {
                const int row = nt * 16 + l15;
                const int cp  = (kc * 4 + quad) ^ (row & 7);
                const short8 kf = *(const short8*)(Ks + (size_t)row * 64 + cp * 8);
                sacc[nt] = __builtin_amdgcn_mfma_f32_16x16x32_bf16(qv, kf, sacc[nt], 0, 0, 0);
            }
        }

        // ---- rel/mask + direct exp ----
#pragma unroll
        for (int reg = 0; reg < 4; ++reg) {
            const int qloc = w * 16 + quad * 4 + reg;
            const unsigned cds = codes[((size_t)(b * SS + q0 + qloc) * 16 + kt) * 16 + l15];
            const float4 r4 = r3v[reg];
#pragma unroll
            for (int nt = 0; nt < 4; ++nt) {
                const unsigned c = (cds >> (8 * nt)) & 0xff;
                float rvv = (c == 0) ? r4.x : (c == 1) ? r4.y : (c == 2) ? r4.z : r4.w;
                const float p = __expf((sacc[nt][reg] + rvv) * 0.125f);
                l_run[reg] += p;
                Ps[(size_t)qloc * 72 + nt * 16 + l15] = f2bf_rne(p);
            }
        }

        // ---- O += P V (per-wave LDS region; same-wave, no barrier) ----
#pragma unroll
        for (int kc = 0; kc < 2; ++kc) {
            const short8 pf = *(const short8*)(Ps + (size_t)(w * 16 + l15) * 72 + kc * 32 + quad * 8);
#pragma unroll
            for (int dt = 0; dt < 4; ++dt) {
                const int d  = dt * 16 + l15;
                const int dg = d >> 3;
                const int kps0 = (kc * 16 + quad * 4) ^ ((dg & 7) * 4);
                const short8 vf = *(const short8*)((const ushort_t*)&Vt2[(size_t)d * 36 + kps0]);
                oacc[dt] = __builtin_amdgcn_mfma_f32_16x16x32_bf16(pf, vf, oacc[dt], 0, 0, 0);
            }
        }
    }

    // ---- epilogue ----
    float* Op = Opart + (size_t)ks * BSD;
    float* lp = lpart + (size_t)ks * BS2 * HH;
#pragma unroll
    for (int reg = 0; reg < 4; ++reg) {
        float ls = l_run[reg];
        ls += __shfl_xor(ls, 1);
        ls += __shfl_xor(ls, 2);
        ls += __shfl_xor(ls, 4);
        ls += __shfl_xor(ls, 8);
        const int orow = b * SS + q0 + w * 16 + quad * 4 + reg;
#pragma unroll
        for (int dt = 0; dt < 4; ++dt)
            Op[(size_t)orow * DD + h * HD + dt * 16 + l15] = oacc[dt][reg];
        if (l15 == 0) lp[(size_t)orow * HH + h] = ls;
    }
}

// ---------------------------------------------------------------------------
// attn_merge: att_bf = (O0+O1+O2+O3) / (l0+l1+l2+l3), bf16 out.
// ---------------------------------------------------------------------------
__global__ __launch_bounds__(256) void attn_merge(
    const float* __restrict__ Opart, const float* __restrict__ lpart,
    ushort_t* __restrict__ att_bf)
{
    int i = blockIdx.x * 256 + threadIdx.x;       // BS*DD/4 threads
    int row = (i * 4) / DD;
    int h   = ((i * 4) % DD) >> 6;
    float lsum = 0.f;
#pragma unroll
    for (int z = 0; z < 4; ++z)
        lsum += lpart[(size_t)z * BS2 * HH + (size_t)row * HH + h];
    float inv = 1.0f / lsum;
    float4 os = ((const float4*)Opart)[i];
#pragma unroll
    for (int z = 1; z < 4; ++z) {
        float4 oz = ((const float4*)(Opart + (size_t)z * BSD))[i];
        os.x += oz.x; os.y += oz.y; os.z += oz.z; os.w += oz.w;
    }
    ushort4 o;
    o.x = f2bf_rne(os.x * inv);
    o.y = f2bf_rne(os.y * inv);
    o.z = f2bf_rne(os.z * inv);
    o.w = f2bf_rne(os.w * inv);
    ((ushort4*)att_bf)[i] = o;
}

// ---------------------------------------------------------------------------
extern "C" void kernel_launch(void* const* d_in, const int* in_sizes, int n_in,
                              void* d_out, int out_size, void* d_ws, size_t ws_size,
                              hipStream_t stream) {
    const float* inp   = (const float*)d_in[0];
    const uchar_t* amask = (const uchar_t*)d_in[1];
    const int*   relm  = (const int*)d_in[2];
    const float* qkv_w = (const float*)d_in[3];
    const float* rel_A = (const float*)d_in[4];
    const float* o_w   = (const float*)d_in[5];
    const float* w1    = (const float*)d_in[6];
    const float* b1    = (const float*)d_in[7];
    const float* w2    = (const float*)d_in[8];
    const float* b2    = (const float*)d_in[9];
    const float* ln1_g = (const float*)d_in[10];
    const float* ln1_b = (const float*)d_in[11];
    const float* ln2_g = (const float*)d_in[12];
    const float* ln2_b = (const float*)d_in[13];
    float* out = (float*)d_out;

    // workspace layout (weight bf16 buffers MUST stay contiguous for cvt_all)
    char* p = (char*)d_ws;
    ushort_t* x_bf   = (ushort_t*)p; p += BSD * 2;
    ushort_t* att_bf = (ushort_t*)p; p += BSD * 2;
    ushort_t* h_bf   = (ushort_t*)p; p += BSD * 2;
    ushort_t* ff_bf  = (ushort_t*)p; p += (size_t)BS2 * DFF * 2;
    ushort_t* qkvw_bf= (ushort_t*)p; p += (size_t)3 * DD * DD * 2;
    ushort_t* ow_bf  = (ushort_t*)p; p += (size_t)DD * DD * 2;
    ushort_t* w1_bf  = (ushort_t*)p; p += (size_t)DFF * DD * 2;
    ushort_t* w2_bf  = (ushort_t*)p; p += (size_t)DD * DFF * 2;
    ushort_t* qkv_bf = (ushort_t*)p; p += (size_t)BS2 * 3 * DD * 2;
    float*    resid  = (float*)p;    p += BSD * 4;
    float*    pool   = (float*)p;    p += 4 * BSD * 4;   // shared partial pool
    float*    lpart  = (float*)p;    p += (size_t)4 * BS2 * HH * 4;
    unsigned* codes  = (unsigned*)p; p += (size_t)BB * SS * SS;   // 2 MB

    // 0. all weight conversions in one launch + codes
    cvt_all<<<(CVT_NT + 255) / 256, 256, 0, stream>>>(qkv_w, o_w, w1, w2, qkvw_bf);
    build_codes<<<(BB * SS * 256) / 256, 256, 0, stream>>>(relm, amask, codes);

    // 1. LN1 -> bf16
    ln_kernel_bf<<<BS2, 256, 0, stream>>>(inp, ln1_g, ln1_b, x_bf);

    // 2. QKV = x @ qkv_w.T -> bf16 : grid (36,16) = 576 blocks
    gemm_tile<false, true, false, false>
        <<<dim3(3 * DD / 64, BS2 / 128, 1), 256, 0, stream>>>(
        x_bf, qkvw_bf, nullptr, qkv_bf, BS2, 3 * DD, DD, DD);

    // 3. attention, k-split x4 : grid 1536 ; merge -> bf16
    attn_mfma_kernel<<<BB * HH * 16 * 4, 256, 0, stream>>>(
        qkv_bf, codes, rel_A, pool, lpart);
    attn_merge<<<(int)(BSD / 4 / 256), 256, 0, stream>>>(pool, lpart, att_bf);

    // 4. o-proj partials (Z=2) : grid (12,16,2) = 384 blocks
    gemm_tile<false, false, false, true>
        <<<dim3(DD / 64, BS2 / 128, 2), 256, 0, stream>>>(
        att_bf, ow_bf, nullptr, pool, BS2, DD, DD, DD / 2);

    // 5. fused: resid = inp + p0 + p1 ; h_bf = LN2(resid)
    merge2_ln_kernel<<<BS2, 256, 0, stream>>>(
        pool, inp, ln2_g, ln2_b, resid, h_bf);

    // 6. ff = relu(h @ w1.T + b1) -> bf16 : grid (48,16) = 768 blocks
    gemm_tile<true, true, true, false>
        <<<dim3(DFF / 64, BS2 / 128, 1), 256, 0, stream>>>(
        h_bf, w1_bf, b1, ff_bf, BS2, DFF, DD, DD);

    // 7. MLP2 partials (Z=4) : grid (12,16,4) = 768 blocks
    gemm_tile<false, false, false, true>
        <<<dim3(DD / 64, BS2 / 128, 4), 256, 0, stream>>>(
        ff_bf, w2_bf, nullptr, pool, BS2, DD, DFF, DFF / 4);

    // 8. out = resid + b2 + p0..p3
    merge4_kernel<<<(int)(BSD / 4 / 256), 256, 0, stream>>>(
        pool, resid, b2, out, (int)(BSD / 4));
}

// Round 9
// 266.933 us; speedup vs baseline: 1.1810x; 1.0313x over previous
//
#include <hip/hip_runtime.h>
#include <hip/hip_bf16.h>

// Problem constants
#define BB 2
#define SS 1024
#define DD 768
#define HH 12
#define HD 64
#define DFF 3072
#define EPS 1e-5f
#define BS2 (BB * SS)            // 2048
#define BSD ((size_t)BS2 * DD)   // 2048*768

typedef unsigned short ushort_t;
typedef unsigned char uchar_t;
using short8 = __attribute__((ext_vector_type(8))) short;
using f32x4  = __attribute__((ext_vector_type(4))) float;

__device__ __forceinline__ ushort_t f2bf_rne(float f) {
    union { float f; unsigned u; } x; x.f = f;
    unsigned r = x.u + 0x7fff + ((x.u >> 16) & 1);
    return (ushort_t)(r >> 16);
}
__device__ __forceinline__ float bf2f(short u) {
    union { unsigned i; float f; } x;
    x.i = ((unsigned)(ushort_t)u) << 16;
    return x.f;
}

// ---------------------------------------------------------------------------
// prep kernel: ONE launch does (a) fp32->bf16 weight conversion, (b) rel/mask
// code packing, (c) LN1. Disjoint blockIdx ranges.
// ---------------------------------------------------------------------------
#define CVT_N1 (3 * DD * DD / 4)
#define CVT_N2 (CVT_N1 + DD * DD / 4)
#define CVT_N3 (CVT_N2 + DFF * DD / 4)
#define CVT_NT (CVT_N3 + DD * DFF / 4)
#define PREP_CVT   (CVT_NT / 256)            // 6912 blocks
#define PREP_CODES (BB * SS)                 // 2048 blocks
#define PREP_LN    BS2                       // 2048 blocks

__global__ __launch_bounds__(256) void prep_kernel(
    const float* __restrict__ qkv_w, const float* __restrict__ o_w,
    const float* __restrict__ w1, const float* __restrict__ w2,
    ushort_t* __restrict__ wdst,
    const int* __restrict__ rel, const uchar_t* __restrict__ mask,
    unsigned* __restrict__ codes,
    const float* __restrict__ x, const float* __restrict__ g,
    const float* __restrict__ b, ushort_t* __restrict__ y)
{
    const int bx = blockIdx.x;
    const int t  = threadIdx.x;
    if (bx < PREP_CVT) {
        int i = bx * 256 + t;
        const float* src; int off;
        if (i < CVT_N1)      { src = qkv_w; off = i; }
        else if (i < CVT_N2) { src = o_w;   off = i - CVT_N1; }
        else if (i < CVT_N3) { src = w1;    off = i - CVT_N2; }
        else                 { src = w2;    off = i - CVT_N3; }
        float4 v = ((const float4*)src)[off];
        ushort4 o;
        o.x = f2bf_rne(v.x); o.y = f2bf_rne(v.y);
        o.z = f2bf_rne(v.z); o.w = f2bf_rne(v.w);
        ((ushort4*)wdst)[i] = o;
        return;
    }
    if (bx < PREP_CVT + PREP_CODES) {
        int tid = (bx - PREP_CVT) * 256 + t;   // (b*S+q)*256 + kt*16 + l15
        int l15 = tid & 15;
        int kt  = (tid >> 4) & 15;
        int q   = (tid >> 8) & (SS - 1);
        int bb  = tid >> 18;
        const int* rrow = rel + ((size_t)(bb * SS + q)) * SS + kt * 64 + l15;
        const uchar_t* mrow = mask + (size_t)bb * SS + kt * 64 + l15;
        unsigned o = 0;
#pragma unroll
        for (int nt = 0; nt < 4; ++nt) {
            unsigned c = mrow[nt * 16] ? 3u : (unsigned)(rrow[nt * 16] + 1);
            o |= c << (8 * nt);
        }
        codes[((size_t)(bb * SS + q) * 16 + kt) * 16 + l15] = o;
        return;
    }
    // ---- LN1 ----
    const int row = bx - PREP_CVT - PREP_CODES;
    const float* xr = x + (size_t)row * DD;
    float s = 0.f, ss = 0.f;
    for (int i = t; i < DD; i += 256) {
        float v = xr[i];
        s += v; ss += v * v;
    }
    for (int off = 32; off; off >>= 1) {
        s  += __shfl_down(s,  off);
        ss += __shfl_down(ss, off);
    }
    __shared__ float reds[4], redss[4], bc[2];
    if ((t & 63) == 0) { reds[t >> 6] = s; redss[t >> 6] = ss; }
    __syncthreads();
    if (t == 0) {
        float S1 = reds[0] + reds[1] + reds[2] + reds[3];
        float S2 = redss[0] + redss[1] + redss[2] + redss[3];
        float mean = S1 / DD;
        float var = S2 / DD - mean * mean;
        bc[0] = mean;
        bc[1] = rsqrtf(var + EPS);
    }
    __syncthreads();
    float mean = bc[0], inv = bc[1];
    ushort_t* yr = y + (size_t)row * DD;
    for (int i = t; i < DD; i += 256) {
        yr[i] = f2bf_rne((xr[i] - mean) * inv * g[i] + b[i]);
    }
}

// ---------------------------------------------------------------------------
// Fused: resid = inp + p0 + p1 ; h_bf = LN(resid). One block per row.
// ---------------------------------------------------------------------------
__global__ __launch_bounds__(256) void merge2_ln_kernel(
    const float* __restrict__ part, const float* __restrict__ inp,
    const float* __restrict__ g, const float* __restrict__ b,
    float* __restrict__ resid, ushort_t* __restrict__ h_bf)
{
    const int row = blockIdx.x;
    const int t = threadIdx.x;
    float4 v = make_float4(0.f, 0.f, 0.f, 0.f);
    const size_t idx = (size_t)row * (DD / 4) + t;
    if (t < DD / 4) {
        v = ((const float4*)inp)[idx];
        float4 p0 = ((const float4*)part)[idx];
        float4 p1 = ((const float4*)(part + BSD))[idx];
        v.x += p0.x + p1.x; v.y += p0.y + p1.y;
        v.z += p0.z + p1.z; v.w += p0.w + p1.w;
        ((float4*)resid)[idx] = v;
    }
    float s  = v.x + v.y + v.z + v.w;
    float ss = v.x * v.x + v.y * v.y + v.z * v.z + v.w * v.w;
    for (int off = 32; off; off >>= 1) {
        s  += __shfl_down(s,  off);
        ss += __shfl_down(ss, off);
    }
    __shared__ float reds[4], redss[4], bc[2];
    if ((t & 63) == 0) { reds[t >> 6] = s; redss[t >> 6] = ss; }
    __syncthreads();
    if (t == 0) {
        float S1 = reds[0] + reds[1] + reds[2] + reds[3];
        float S2 = redss[0] + redss[1] + redss[2] + redss[3];
        float mean = S1 / DD;
        float var = S2 / DD - mean * mean;
        bc[0] = mean;
        bc[1] = rsqrtf(var + EPS);
    }
    __syncthreads();
    if (t < DD / 4) {
        const float mean = bc[0], inv = bc[1];
        float4 gv = ((const float4*)g)[t];
        float4 bv = ((const float4*)b)[t];
        ushort4 o;
        o.x = f2bf_rne((v.x - mean) * inv * gv.x + bv.x);
        o.y = f2bf_rne((v.y - mean) * inv * gv.y + bv.y);
        o.z = f2bf_rne((v.z - mean) * inv * gv.z + bv.z);
        o.w = f2bf_rne((v.w - mean) * inv * gv.w + bv.w);
        ((ushort4*)h_bf)[idx] = o;
    }
}

// ---------------------------------------------------------------------------
// merge4: out = resid + b2 + sum of 4 partial slices.
// ---------------------------------------------------------------------------
__global__ __launch_bounds__(256) void merge4_kernel(
    const float* __restrict__ part, const float* __restrict__ resid,
    const float* __restrict__ b2, float* __restrict__ outp, int n4)
{
    int i = blockIdx.x * 256 + threadIdx.x;
    if (i >= n4) return;
    float4 v = ((const float4*)resid)[i];
    int col4 = (i * 4) % DD;
    float4 bv = *(const float4*)(b2 + col4);
    v.x += bv.x; v.y += bv.y; v.z += bv.z; v.w += bv.w;
#pragma unroll
    for (int z = 0; z < 4; ++z) {
        float4 pz = ((const float4*)(part + (size_t)z * BSD))[i];
        v.x += pz.x; v.y += pz.y; v.z += pz.z; v.w += pz.w;
    }
    ((float4*)outp)[i] = v;
}

// ---------------------------------------------------------------------------
// LDS-staged MFMA GEMM, 64x128 tile, BK=64, 256 threads = 4 waves.
// Wave w: rows [(w&1)*32, +32), cols [(w>>1)*64, +64); per BK=64 iter each
// wave does 16 MFMA (2 k-steps x 2x4 sub-tiles) against 12 ds_read_b128.
// LDS chunk layout: As slot = kq*64+row (kq 0..7), Bs slot = kq*128+row.
// grid = (N/128, M/64, Z); Ksplit = K/Z (divisible by 64).
// ---------------------------------------------------------------------------
template <bool RELU, bool OUT_BF16, bool HAS_BIAS, bool PARTIAL>
__global__ __launch_bounds__(256) void gemm_tile(
    const ushort_t* __restrict__ A, const ushort_t* __restrict__ W,
    const float* __restrict__ bias, void* __restrict__ Cout,
    int M, int N, int K, int Ksplit)
{
    __shared__ __align__(16) ushort_t As[512 * 8];    // 8 KB  (64 rows x 8 kq)
    __shared__ __align__(16) ushort_t Bs[1024 * 8];   // 16 KB (128 rows x 8 kq)

    const int t  = threadIdx.x;
    const int n0 = blockIdx.x * 128;
    const int m0 = blockIdx.y * 64;
    const int kb = blockIdx.z * Ksplit;
    const int w  = t >> 6;
    const int l  = t & 63;
    const int wm = (w & 1) * 32;
    const int wn = (w >> 1) * 64;
    const int l15  = l & 15;
    const int quad = l >> 4;

    // A staging: slot t (kq=t>>6, row=t&63) and slot t+256 (kq+4)
    const ushort_t* gA = A + (size_t)(m0 + (t & 63)) * K + kb + (t >> 6) * 8;
    ushort_t* lA = &As[(size_t)t * 8];
    // B staging: slots t+256*ii (kq=(t>>7)+2*ii, row=t&127), ii=0..3
    const ushort_t* gB = W + (size_t)(n0 + (t & 127)) * K + kb + (t >> 7) * 8;
    ushort_t* lB = &Bs[(size_t)t * 8];

    f32x4 acc[2][4] = {};

    for (int k0 = 0; k0 < Ksplit; k0 += 64) {
        __syncthreads();
        __builtin_amdgcn_global_load_lds(
            (const __attribute__((address_space(1))) unsigned int*)(gA + k0),
            (__attribute__((address_space(3))) unsigned int*)lA, 16, 0, 0);
        __builtin_amdgcn_global_load_lds(
            (const __attribute__((address_space(1))) unsigned int*)(gA + k0 + 32),
            (__attribute__((address_space(3))) unsigned int*)(lA + 256 * 8), 16, 0, 0);
#pragma unroll
        for (int ii = 0; ii < 4; ++ii)
            __builtin_amdgcn_global_load_lds(
                (const __attribute__((address_space(1))) unsigned int*)(gB + k0 + ii * 16),
                (__attribute__((address_space(3))) unsigned int*)(lB + (size_t)ii * 256 * 8),
                16, 0, 0);
        __syncthreads();

#pragma unroll
        for (int ks = 0; ks < 2; ++ks) {
            const ushort_t* aptr = &As[(size_t)((ks * 4 + quad) * 64 + wm + l15) * 8];
            const ushort_t* bptr = &Bs[(size_t)((ks * 4 + quad) * 128 + wn + l15) * 8];
            short8 af[2], bf[4];
#pragma unroll
            for (int i = 0; i < 2; ++i)
                af[i] = *(const short8*)(aptr + (size_t)i * 16 * 8);
#pragma unroll
            for (int j = 0; j < 4; ++j)
                bf[j] = *(const short8*)(bptr + (size_t)j * 16 * 8);
#pragma unroll
            for (int i = 0; i < 2; ++i)
#pragma unroll
                for (int j = 0; j < 4; ++j)
                    acc[i][j] = __builtin_amdgcn_mfma_f32_16x16x32_bf16(
                        af[i], bf[j], acc[i][j], 0, 0, 0);
        }
    }

    // epilogue: C/D layout col=lane&15, row=(lane>>4)*4+reg
    if (PARTIAL) {
        float* Cp = (float*)Cout + (size_t)blockIdx.z * ((size_t)M * N);
#pragma unroll
        for (int i = 0; i < 2; ++i) {
            const int row = m0 + wm + i * 16 + quad * 4;
#pragma unroll
            for (int j = 0; j < 4; ++j) {
                const int col = n0 + wn + j * 16 + l15;
#pragma unroll
                for (int r = 0; r < 4; ++r)
                    Cp[(size_t)(row + r) * N + col] = acc[i][j][r];
            }
        }
    } else {
#pragma unroll
        for (int i = 0; i < 2; ++i) {
            const int row = m0 + wm + i * 16 + quad * 4;
#pragma unroll
            for (int j = 0; j < 4; ++j) {
                const int col = n0 + wn + j * 16 + l15;
                const float bv = HAS_BIAS ? bias[col] : 0.f;
#pragma unroll
                for (int r = 0; r < 4; ++r) {
                    float v = acc[i][j][r] + bv;
                    if (RELU) v = fmaxf(v, 0.f);
                    if (OUT_BF16)
                        ((ushort_t*)Cout)[(size_t)(row + r) * N + col] = f2bf_rne(v);
                    else
                        ((float*)Cout)[(size_t)(row + r) * N + col] = v;
                }
            }
        }
    }
}

// ---------------------------------------------------------------------------
// MFMA flash attention, K-SPLIT x2, direct exp (no online max: logits are
// small; masked entries hit -2.4e31 sentinel -> exp = 0).
// Block per (b, h, qtile, ks): grid = 2*12*16*2 = 768.
// Emits bf16 unnormalized O partials + fp32 l partials.
// ---------------------------------------------------------------------------
__global__ __launch_bounds__(256) void attn_mfma_kernel(
    const ushort_t* __restrict__ qkv,      // (B*S, 2304) bf16
    const unsigned* __restrict__ codes,    // packed rel/mask codes
    const float* __restrict__ rel_A,       // (3, 64) fp32
    ushort_t* __restrict__ Opart,          // [2][BS*DD] bf16 unnormalized
    float* __restrict__ lpart)             // [2][BS*HH] fp32 row sums
{
    __shared__ __align__(16) ushort_t Ks[64 * 64];
    __shared__ __align__(16) unsigned Vt2[64 * 36];
    __shared__ __align__(16) ushort_t Ps[64 * 72];
    __shared__ __align__(16) float r3s[64][4];

    const int bx = blockIdx.x;
    const int ks = bx & 1;
    const int qt = (bx >> 1) & 15;
    const int h  = (bx >> 5) % HH;
    const int b  = bx / (32 * HH);
    const int q0 = qt * 64;
    const int t  = threadIdx.x;
    const int w  = t >> 6;
    const int l  = t & 63;
    const int l15  = l & 15;
    const int quad = l >> 4;

    const size_t qrow = (size_t)(b * SS + q0 + w * 16 + l15) * (3 * DD) + h * HD;
    const short8 qf0 = *(const short8*)(qkv + qrow + quad * 8);
    const short8 qf1 = *(const short8*)(qkv + qrow + 32 + quad * 8);

    {
        float rv[3];
#pragma unroll
        for (int c = 0; c < 3; ++c) {
            const float* a = rel_A + c * HD + quad * 8;
            float acc = 0.f;
#pragma unroll
            for (int j = 0; j < 8; ++j) acc += bf2f(qf0[j]) * a[j];
#pragma unroll
            for (int j = 0; j < 8; ++j) acc += bf2f(qf1[j]) * a[32 + j];
            acc += __shfl_xor(acc, 16);
            acc += __shfl_xor(acc, 32);
            rv[c] = acc;
        }
        if (quad == 0) {
            float4 f4 = make_float4(rv[0], rv[1], rv[2], -2.4e31f);
            *(float4*)&r3s[w * 16 + l15][0] = f4;
        }
    }
    __syncthreads();
    float4 r3v[4];
#pragma unroll
    for (int reg = 0; reg < 4; ++reg)
        r3v[reg] = *(const float4*)&r3s[w * 16 + quad * 4 + reg][0];

    float l_run[4] = {0.f, 0.f, 0.f, 0.f};
    f32x4 oacc[4] = {};

    for (int kt = ks * 8; kt < ks * 8 + 8; ++kt) {
        const int k0 = kt * 64;
        __syncthreads();
        // ---- stage K (XOR-swizzled chunks) ----
        {
            const int r  = t >> 3;
            const int cp = t & 7;
            const int cl  = cp ^ (r & 7);
            const ushort_t* g = qkv + (size_t)(b * SS + k0 + r) * (3 * DD) + DD + h * HD + cl * 8;
            __builtin_amdgcn_global_load_lds(
                (const __attribute__((address_space(1))) unsigned*)g,
                (__attribute__((address_space(3))) unsigned*)(Ks + (size_t)t * 8), 16, 0, 0);
            const int r2  = r + 32;
            const int cl2 = cp ^ (r2 & 7);
            const ushort_t* g2 = qkv + (size_t)(b * SS + k0 + r2) * (3 * DD) + DD + h * HD + cl2 * 8;
            __builtin_amdgcn_global_load_lds(
                (const __attribute__((address_space(1))) unsigned*)g2,
                (__attribute__((address_space(3))) unsigned*)(Ks + (size_t)(t + 256) * 8), 16, 0, 0);
        }
        // ---- stage V transposed (bf16 kpairs, swizzled) ----
        {
            const int kp = t >> 3;
            const int dg = t & 7;
            const ushort_t* g = qkv + (size_t)(b * SS + k0 + 2 * kp) * (3 * DD) + 2 * DD + h * HD + dg * 8;
            short8 va = *(const short8*)g;
            short8 vb = *(const short8*)(g + 3 * DD);
            const int kps = kp ^ ((dg & 7) * 4);
#pragma unroll
            for (int i = 0; i < 8; ++i)
                Vt2[(size_t)(dg * 8 + i) * 36 + kps] =
                    (unsigned)(ushort_t)va[i] | ((unsigned)(ushort_t)vb[i] << 16);
        }
        __syncthreads();

        // ---- S = Q K^T ----
        f32x4 sacc[4] = {};
#pragma unroll
        for (int kc = 0; kc < 2; ++kc) {
            const short8 qv = kc ? qf1 : qf0;
#pragma unroll
            for (int nt = 0; nt < 4; ++nt) {
                const int row = nt * 16 + l15;
                const int cp  = (kc * 4 + quad) ^ (row & 7);
                const short8 kf = *(const short8*)(Ks + (size_t)row * 64 + cp * 8);
                sacc[nt] = __builtin_amdgcn_mfma_f32_16x16x32_bf16(qv, kf, sacc[nt], 0, 0, 0);
            }
        }

        // ---- rel/mask + direct exp ----
#pragma unroll
        for (int reg = 0; reg < 4; ++reg) {
            const int qloc = w * 16 + quad * 4 + reg;
            const unsigned cds = codes[((size_t)(b * SS + q0 + qloc) * 16 + kt) * 16 + l15];
            const float4 r4 = r3v[reg];
#pragma unroll
            for (int nt = 0; nt < 4; ++nt) {
                const unsigned c = (cds >> (8 * nt)) & 0xff;
                float rvv = (c == 0) ? r4.x : (c == 1) ? r4.y : (c == 2) ? r4.z : r4.w;
                const float p = __expf((sacc[nt][reg] + rvv) * 0.125f);
                l_run[reg] += p;
                Ps[(size_t)qloc * 72 + nt * 16 + l15] = f2bf_rne(p);
            }
        }

        // ---- O += P V (per-wave LDS region; same-wave, no barrier) ----
#pragma unroll
        for (int kc = 0; kc < 2; ++kc) {
            const short8 pf = *(const short8*)(Ps + (size_t)(w * 16 + l15) * 72 + kc * 32 + quad * 8);
#pragma unroll
            for (int dt = 0; dt < 4; ++dt) {
                const int d  = dt * 16 + l15;
                const int dg = d >> 3;
                const int kps0 = (kc * 16 + quad * 4) ^ ((dg & 7) * 4);
                const short8 vf = *(const short8*)((const ushort_t*)&Vt2[(size_t)d * 36 + kps0]);
                oacc[dt] = __builtin_amdgcn_mfma_f32_16x16x32_bf16(pf, vf, oacc[dt], 0, 0, 0);
            }
        }
    }

    // ---- epilogue: reduce l across the 16-lane row group; emit partials ----
    ushort_t* Op = Opart + (size_t)ks * BSD;
    float* lp = lpart + (size_t)ks * BS2 * HH;
#pragma unroll
    for (int reg = 0; reg < 4; ++reg) {
        float ls = l_run[reg];
        ls += __shfl_xor(ls, 1);
        ls += __shfl_xor(ls, 2);
        ls += __shfl_xor(ls, 4);
        ls += __shfl_xor(ls, 8);
        const int orow = b * SS + q0 + w * 16 + quad * 4 + reg;
#pragma unroll
        for (int dt = 0; dt < 4; ++dt)
            Op[(size_t)orow * DD + h * HD + dt * 16 + l15] = f2bf_rne(oacc[dt][reg]);
        if (l15 == 0) lp[(size_t)orow * HH + h] = ls;
    }
}

// ---------------------------------------------------------------------------
// attn_merge: att_bf = (O0 + O1) / (l0 + l1), bf16 partials in, bf16 out.
// ---------------------------------------------------------------------------
__global__ __launch_bounds__(256) void attn_merge(
    const ushort_t* __restrict__ Opart, const float* __restrict__ lpart,
    ushort_t* __restrict__ att_bf)
{
    int i = blockIdx.x * 256 + threadIdx.x;       // BS*DD/4 threads
    int row = (i * 4) / DD;
    int h   = ((i * 4) % DD) >> 6;
    float l0 = lpart[(size_t)row * HH + h];
    float l1 = lpart[(size_t)BS2 * HH + (size_t)row * HH + h];
    float inv = 1.0f / (l0 + l1);
    ushort4 a = ((const ushort4*)Opart)[i];
    ushort4 b = ((const ushort4*)(Opart + BSD))[i];
    ushort4 o;
    o.x = f2bf_rne((bf2f(a.x) + bf2f(b.x)) * inv);
    o.y = f2bf_rne((bf2f(a.y) + bf2f(b.y)) * inv);
    o.z = f2bf_rne((bf2f(a.z) + bf2f(b.z)) * inv);
    o.w = f2bf_rne((bf2f(a.w) + bf2f(b.w)) * inv);
    ((ushort4*)att_bf)[i] = o;
}

// ---------------------------------------------------------------------------
extern "C" void kernel_launch(void* const* d_in, const int* in_sizes, int n_in,
                              void* d_out, int out_size, void* d_ws, size_t ws_size,
                              hipStream_t stream) {
    const float* inp   = (const float*)d_in[0];
    const uchar_t* amask = (const uchar_t*)d_in[1];
    const int*   relm  = (const int*)d_in[2];
    const float* qkv_w = (const float*)d_in[3];
    const float* rel_A = (const float*)d_in[4];
    const float* o_w   = (const float*)d_in[5];
    const float* w1    = (const float*)d_in[6];
    const float* b1    = (const float*)d_in[7];
    const float* w2    = (const float*)d_in[8];
    const float* b2    = (const float*)d_in[9];
    const float* ln1_g = (const float*)d_in[10];
    const float* ln1_b = (const float*)d_in[11];
    const float* ln2_g = (const float*)d_in[12];
    const float* ln2_b = (const float*)d_in[13];
    float* out = (float*)d_out;

    // workspace layout (weight bf16 buffers MUST stay contiguous for cvt)
    char* p = (char*)d_ws;
    ushort_t* x_bf   = (ushort_t*)p; p += BSD * 2;
    ushort_t* att_bf = (ushort_t*)p; p += BSD * 2;
    ushort_t* h_bf   = (ushort_t*)p; p += BSD * 2;
    ushort_t* ff_bf  = (ushort_t*)p; p += (size_t)BS2 * DFF * 2;
    ushort_t* qkvw_bf= (ushort_t*)p; p += (size_t)3 * DD * DD * 2;
    ushort_t* ow_bf  = (ushort_t*)p; p += (size_t)DD * DD * 2;
    ushort_t* w1_bf  = (ushort_t*)p; p += (size_t)DFF * DD * 2;
    ushort_t* w2_bf  = (ushort_t*)p; p += (size_t)DD * DFF * 2;
    ushort_t* qkv_bf = (ushort_t*)p; p += (size_t)BS2 * 3 * DD * 2;
    float*    resid  = (float*)p;    p += BSD * 4;
    float*    pool   = (float*)p;    p += 4 * BSD * 4;   // fp32 partial pool
    ushort_t* Opart  = (ushort_t*)p; p += 2 * BSD * 2;   // bf16 attn partials
    float*    lpart  = (float*)p;    p += (size_t)2 * BS2 * HH * 4;
    unsigned* codes  = (unsigned*)p; p += (size_t)BB * SS * SS;   // 2 MB

    // 0. prep: weight cvt + codes + LN1, one launch
    prep_kernel<<<PREP_CVT + PREP_CODES + PREP_LN, 256, 0, stream>>>(
        qkv_w, o_w, w1, w2, qkvw_bf, relm, amask, codes,
        inp, ln1_g, ln1_b, x_bf);

    // 1. QKV = x @ qkv_w.T -> bf16 : grid (18,32) = 576 blocks
    gemm_tile<false, true, false, false>
        <<<dim3(3 * DD / 128, BS2 / 64, 1), 256, 0, stream>>>(
        x_bf, qkvw_bf, nullptr, qkv_bf, BS2, 3 * DD, DD, DD);

    // 2. attention, k-split x2 : grid 768 ; merge -> bf16
    attn_mfma_kernel<<<BB * HH * 16 * 2, 256, 0, stream>>>(
        qkv_bf, codes, rel_A, Opart, lpart);
    attn_merge<<<(int)(BSD / 4 / 256), 256, 0, stream>>>(Opart, lpart, att_bf);

    // 3. o-proj partials (Z=2) : grid (6,32,2) = 384 blocks
    gemm_tile<false, false, false, true>
        <<<dim3(DD / 128, BS2 / 64, 2), 256, 0, stream>>>(
        att_bf, ow_bf, nullptr, pool, BS2, DD, DD, DD / 2);

    // 4. fused: resid = inp + p0 + p1 ; h_bf = LN2(resid)
    merge2_ln_kernel<<<BS2, 256, 0, stream>>>(
        pool, inp, ln2_g, ln2_b, resid, h_bf);

    // 5. ff = relu(h @ w1.T + b1) -> bf16 : grid (24,32) = 768 blocks
    gemm_tile<true, true, true, false>
        <<<dim3(DFF / 128, BS2 / 64, 1), 256, 0, stream>>>(
        h_bf, w1_bf, b1, ff_bf, BS2, DFF, DD, DD);

    // 6. MLP2 partials (Z=4) : grid (6,32,4) = 768 blocks
    gemm_tile<false, false, false, true>
        <<<dim3(DD / 128, BS2 / 64, 4), 256, 0, stream>>>(
        ff_bf, w2_bf, nullptr, pool, BS2, DD, DFF, DFF / 4);

    // 7. out = resid + b2 + p0..p3
    merge4_kernel<<<(int)(BSD / 4 / 256), 256, 0, stream>>>(
        pool, resid, b2, out, (int)(BSD / 4));
}

// Round 10
// 265.801 us; speedup vs baseline: 1.1860x; 1.0043x over previous
//
#include <hip/hip_runtime.h>
#include <hip/hip_bf16.h>

// Problem constants
#define BB 2
#define SS 1024
#define DD 768
#define HH 12
#define HD 64
#define DFF 3072
#define EPS 1e-5f
#define BS2 (BB * SS)            // 2048
#define BSD ((size_t)BS2 * DD)   // 2048*768

typedef unsigned short ushort_t;
typedef unsigned char uchar_t;
using short8 = __attribute__((ext_vector_type(8))) short;
using f32x4  = __attribute__((ext_vector_type(4))) float;

__device__ __forceinline__ ushort_t f2bf_rne(float f) {
    union { float f; unsigned u; } x; x.f = f;
    unsigned r = x.u + 0x7fff + ((x.u >> 16) & 1);
    return (ushort_t)(r >> 16);
}
__device__ __forceinline__ float bf2f(short u) {
    union { unsigned i; float f; } x;
    x.i = ((unsigned)(ushort_t)u) << 16;
    return x.f;
}

// ---------------------------------------------------------------------------
// prep kernel: ONE launch does (a) fp32->bf16 weight conversion, (b) rel/mask
// code packing, (c) LN1. Disjoint blockIdx ranges.
// ---------------------------------------------------------------------------
#define CVT_N1 (3 * DD * DD / 4)
#define CVT_N2 (CVT_N1 + DD * DD / 4)
#define CVT_N3 (CVT_N2 + DFF * DD / 4)
#define CVT_NT (CVT_N3 + DD * DFF / 4)
#define PREP_CVT   (CVT_NT / 256)
#define PREP_CODES (BB * SS)
#define PREP_LN    BS2

__global__ __launch_bounds__(256) void prep_kernel(
    const float* __restrict__ qkv_w, const float* __restrict__ o_w,
    const float* __restrict__ w1, const float* __restrict__ w2,
    ushort_t* __restrict__ wdst,
    const int* __restrict__ rel, const uchar_t* __restrict__ mask,
    unsigned* __restrict__ codes,
    const float* __restrict__ x, const float* __restrict__ g,
    const float* __restrict__ b, ushort_t* __restrict__ y)
{
    const int bx = blockIdx.x;
    const int t  = threadIdx.x;
    if (bx < PREP_CVT) {
        int i = bx * 256 + t;
        const float* src; int off;
        if (i < CVT_N1)      { src = qkv_w; off = i; }
        else if (i < CVT_N2) { src = o_w;   off = i - CVT_N1; }
        else if (i < CVT_N3) { src = w1;    off = i - CVT_N2; }
        else                 { src = w2;    off = i - CVT_N3; }
        float4 v = ((const float4*)src)[off];
        ushort4 o;
        o.x = f2bf_rne(v.x); o.y = f2bf_rne(v.y);
        o.z = f2bf_rne(v.z); o.w = f2bf_rne(v.w);
        ((ushort4*)wdst)[i] = o;
        return;
    }
    if (bx < PREP_CVT + PREP_CODES) {
        int tid = (bx - PREP_CVT) * 256 + t;
        int l15 = tid & 15;
        int kt  = (tid >> 4) & 15;
        int q   = (tid >> 8) & (SS - 1);
        int bb  = tid >> 18;
        const int* rrow = rel + ((size_t)(bb * SS + q)) * SS + kt * 64 + l15;
        const uchar_t* mrow = mask + (size_t)bb * SS + kt * 64 + l15;
        unsigned o = 0;
#pragma unroll
        for (int nt = 0; nt < 4; ++nt) {
            unsigned c = mrow[nt * 16] ? 3u : (unsigned)(rrow[nt * 16] + 1);
            o |= c << (8 * nt);
        }
        codes[((size_t)(bb * SS + q) * 16 + kt) * 16 + l15] = o;
        return;
    }
    // ---- LN1 ----
    const int row = bx - PREP_CVT - PREP_CODES;
    const float* xr = x + (size_t)row * DD;
    float s = 0.f, ss = 0.f;
    for (int i = t; i < DD; i += 256) {
        float v = xr[i];
        s += v; ss += v * v;
    }
    for (int off = 32; off; off >>= 1) {
        s  += __shfl_down(s,  off);
        ss += __shfl_down(ss, off);
    }
    __shared__ float reds[4], redss[4], bc[2];
    if ((t & 63) == 0) { reds[t >> 6] = s; redss[t >> 6] = ss; }
    __syncthreads();
    if (t == 0) {
        float S1 = reds[0] + reds[1] + reds[2] + reds[3];
        float S2 = redss[0] + redss[1] + redss[2] + redss[3];
        float mean = S1 / DD;
        float var = S2 / DD - mean * mean;
        bc[0] = mean;
        bc[1] = rsqrtf(var + EPS);
    }
    __syncthreads();
    float mean = bc[0], inv = bc[1];
    ushort_t* yr = y + (size_t)row * DD;
    for (int i = t; i < DD; i += 256) {
        yr[i] = f2bf_rne((xr[i] - mean) * inv * g[i] + b[i]);
    }
}

// ---------------------------------------------------------------------------
// Fused: resid = inp + p0 + p1 (bf16 partials) ; h_bf = LN(resid).
// ---------------------------------------------------------------------------
__global__ __launch_bounds__(256) void merge2_ln_kernel(
    const ushort_t* __restrict__ part, const float* __restrict__ inp,
    const float* __restrict__ g, const float* __restrict__ b,
    float* __restrict__ resid, ushort_t* __restrict__ h_bf)
{
    const int row = blockIdx.x;
    const int t = threadIdx.x;
    float4 v = make_float4(0.f, 0.f, 0.f, 0.f);
    const size_t idx = (size_t)row * (DD / 4) + t;
    if (t < DD / 4) {
        v = ((const float4*)inp)[idx];
        ushort4 p0 = ((const ushort4*)part)[idx];
        ushort4 p1 = ((const ushort4*)(part + BSD))[idx];
        v.x += bf2f(p0.x) + bf2f(p1.x);
        v.y += bf2f(p0.y) + bf2f(p1.y);
        v.z += bf2f(p0.z) + bf2f(p1.z);
        v.w += bf2f(p0.w) + bf2f(p1.w);
        ((float4*)resid)[idx] = v;
    }
    float s  = v.x + v.y + v.z + v.w;
    float ss = v.x * v.x + v.y * v.y + v.z * v.z + v.w * v.w;
    for (int off = 32; off; off >>= 1) {
        s  += __shfl_down(s,  off);
        ss += __shfl_down(ss, off);
    }
    __shared__ float reds[4], redss[4], bc[2];
    if ((t & 63) == 0) { reds[t >> 6] = s; redss[t >> 6] = ss; }
    __syncthreads();
    if (t == 0) {
        float S1 = reds[0] + reds[1] + reds[2] + reds[3];
        float S2 = redss[0] + redss[1] + redss[2] + redss[3];
        float mean = S1 / DD;
        float var = S2 / DD - mean * mean;
        bc[0] = mean;
        bc[1] = rsqrtf(var + EPS);
    }
    __syncthreads();
    if (t < DD / 4) {
        const float mean = bc[0], inv = bc[1];
        float4 gv = ((const float4*)g)[t];
        float4 bv = ((const float4*)b)[t];
        ushort4 o;
        o.x = f2bf_rne((v.x - mean) * inv * gv.x + bv.x);
        o.y = f2bf_rne((v.y - mean) * inv * gv.y + bv.y);
        o.z = f2bf_rne((v.z - mean) * inv * gv.z + bv.z);
        o.w = f2bf_rne((v.w - mean) * inv * gv.w + bv.w);
        ((ushort4*)h_bf)[idx] = o;
    }
}

// ---------------------------------------------------------------------------
// merge4: out = resid + b2 + sum of 4 bf16 partial slices.
// ---------------------------------------------------------------------------
__global__ __launch_bounds__(256) void merge4_kernel(
    const ushort_t* __restrict__ part, const float* __restrict__ resid,
    const float* __restrict__ b2, float* __restrict__ outp, int n4)
{
    int i = blockIdx.x * 256 + threadIdx.x;
    if (i >= n4) return;
    float4 v = ((const float4*)resid)[i];
    int col4 = (i * 4) % DD;
    float4 bv = *(const float4*)(b2 + col4);
    v.x += bv.x; v.y += bv.y; v.z += bv.z; v.w += bv.w;
#pragma unroll
    for (int z = 0; z < 4; ++z) {
        ushort4 pz = ((const ushort4*)(part + (size_t)z * BSD))[i];
        v.x += bf2f(pz.x); v.y += bf2f(pz.y);
        v.z += bf2f(pz.z); v.w += bf2f(pz.w);
    }
    ((float4*)outp)[i] = v;
}

// ---------------------------------------------------------------------------
// LDS DOUBLE-BUFFERED MFMA GEMM, 64x128 tile, BK=64, 256 threads = 4 waves.
// One __syncthreads per K-iter: prefetch tile k+1 (global_load_lds -> buf^1)
// is issued right after the barrier, then compute runs on buf — the barrier's
// vmcnt drain at the top of the next iter waits ~nothing (loads had a full
// compute phase in flight). LDS 48 KB -> 3 blocks/CU.
// grid = (N/128, M/64, Z); Ksplit = K/Z (divisible by 64).
// PARTIAL: write bf16 slice per z.
// ---------------------------------------------------------------------------
template <bool RELU, bool OUT_BF16, bool HAS_BIAS, bool PARTIAL>
__global__ __launch_bounds__(256) void gemm_tile(
    const ushort_t* __restrict__ A, const ushort_t* __restrict__ W,
    const float* __restrict__ bias, void* __restrict__ Cout,
    int M, int N, int K, int Ksplit)
{
    __shared__ __align__(16) ushort_t As[2][512 * 8];    // 2 x 8 KB
    __shared__ __align__(16) ushort_t Bs[2][1024 * 8];   // 2 x 16 KB

    const int t  = threadIdx.x;
    const int n0 = blockIdx.x * 128;
    const int m0 = blockIdx.y * 64;
    const int kb = blockIdx.z * Ksplit;
    const int w  = t >> 6;
    const int l  = t & 63;
    const int wm = (w & 1) * 32;
    const int wn = (w >> 1) * 64;
    const int l15  = l & 15;
    const int quad = l >> 4;

    const ushort_t* gA = A + (size_t)(m0 + (t & 63)) * K + kb + (t >> 6) * 8;
    const ushort_t* gB = W + (size_t)(n0 + (t & 127)) * K + kb + (t >> 7) * 8;

    f32x4 acc[2][4] = {};

    // prologue prefetch into buf 0
    {
        ushort_t* lA = &As[0][(size_t)t * 8];
        ushort_t* lB = &Bs[0][(size_t)t * 8];
        __builtin_amdgcn_global_load_lds(
            (const __attribute__((address_space(1))) unsigned int*)(gA),
            (__attribute__((address_space(3))) unsigned int*)lA, 16, 0, 0);
        __builtin_amdgcn_global_load_lds(
            (const __attribute__((address_space(1))) unsigned int*)(gA + 32),
            (__attribute__((address_space(3))) unsigned int*)(lA + 256 * 8), 16, 0, 0);
#pragma unroll
        for (int ii = 0; ii < 4; ++ii)
            __builtin_amdgcn_global_load_lds(
                (const __attribute__((address_space(1))) unsigned int*)(gB + ii * 16),
                (__attribute__((address_space(3))) unsigned int*)(lB + (size_t)ii * 256 * 8),
                16, 0, 0);
    }

    const int nIter = Ksplit >> 6;
    for (int it = 0; it < nIter; ++it) {
        __syncthreads();    // drains vmcnt: buf[it&1] ready; prev reads done
        if (it + 1 < nIter) {
            const int k0 = (it + 1) << 6;
            const int nb = (it + 1) & 1;
            ushort_t* lA = &As[nb][(size_t)t * 8];
            ushort_t* lB = &Bs[nb][(size_t)t * 8];
            __builtin_amdgcn_global_load_lds(
                (const __attribute__((address_space(1))) unsigned int*)(gA + k0),
                (__attribute__((address_space(3))) unsigned int*)lA, 16, 0, 0);
            __builtin_amdgcn_global_load_lds(
                (const __attribute__((address_space(1))) unsigned int*)(gA + k0 + 32),
                (__attribute__((address_space(3))) unsigned int*)(lA + 256 * 8), 16, 0, 0);
#pragma unroll
            for (int ii = 0; ii < 4; ++ii)
                __builtin_amdgcn_global_load_lds(
                    (const __attribute__((address_space(1))) unsigned int*)(gB + k0 + ii * 16),
                    (__attribute__((address_space(3))) unsigned int*)(lB + (size_t)ii * 256 * 8),
                    16, 0, 0);
        }
        const int buf = it & 1;
#pragma unroll
        for (int ks = 0; ks < 2; ++ks) {
            const ushort_t* aptr = &As[buf][(size_t)((ks * 4 + quad) * 64 + wm + l15) * 8];
            const ushort_t* bptr = &Bs[buf][(size_t)((ks * 4 + quad) * 128 + wn + l15) * 8];
            short8 af[2], bf[4];
#pragma unroll
            for (int i = 0; i < 2; ++i)
                af[i] = *(const short8*)(aptr + (size_t)i * 16 * 8);
#pragma unroll
            for (int j = 0; j < 4; ++j)
                bf[j] = *(const short8*)(bptr + (size_t)j * 16 * 8);
#pragma unroll
            for (int i = 0; i < 2; ++i)
#pragma unroll
                for (int j = 0; j < 4; ++j)
                    acc[i][j] = __builtin_amdgcn_mfma_f32_16x16x32_bf16(
                        af[i], bf[j], acc[i][j], 0, 0, 0);
        }
    }

    // epilogue: C/D layout col=lane&15, row=(lane>>4)*4+reg
    if (PARTIAL) {
        ushort_t* Cp = (ushort_t*)Cout + (size_t)blockIdx.z * ((size_t)M * N);
#pragma unroll
        for (int i = 0; i < 2; ++i) {
            const int row = m0 + wm + i * 16 + quad * 4;
#pragma unroll
            for (int j = 0; j < 4; ++j) {
                const int col = n0 + wn + j * 16 + l15;
#pragma unroll
                for (int r = 0; r < 4; ++r)
                    Cp[(size_t)(row + r) * N + col] = f2bf_rne(acc[i][j][r]);
            }
        }
    } else {
#pragma unroll
        for (int i = 0; i < 2; ++i) {
            const int row = m0 + wm + i * 16 + quad * 4;
#pragma unroll
            for (int j = 0; j < 4; ++j) {
                const int col = n0 + wn + j * 16 + l15;
                const float bv = HAS_BIAS ? bias[col] : 0.f;
#pragma unroll
                for (int r = 0; r < 4; ++r) {
                    float v = acc[i][j][r] + bv;
                    if (RELU) v = fmaxf(v, 0.f);
                    if (OUT_BF16)
                        ((ushort_t*)Cout)[(size_t)(row + r) * N + col] = f2bf_rne(v);
                    else
                        ((float*)Cout)[(size_t)(row + r) * N + col] = v;
                }
            }
        }
    }
}

// ---------------------------------------------------------------------------
// MFMA flash attention, K-SPLIT x2, direct exp, LDS DOUBLE-BUFFERED staging:
// per k-tile one barrier; K dma + V reg-loads for tile i+1 issued before
// compute of tile i; V ds_writes after compute (loads arrived meanwhile).
// Block per (b, h, qtile, ks): grid = 768. LDS 44 KB -> 3 blocks/CU.
// ---------------------------------------------------------------------------
__global__ __launch_bounds__(256) void attn_mfma_kernel(
    const ushort_t* __restrict__ qkv,      // (B*S, 2304) bf16
    const unsigned* __restrict__ codes,    // packed rel/mask codes
    const float* __restrict__ rel_A,       // (3, 64) fp32
    ushort_t* __restrict__ Opart,          // [2][BS*DD] bf16 unnormalized
    float* __restrict__ lpart)             // [2][BS*HH] fp32 row sums
{
    __shared__ __align__(16) ushort_t Ks[2][64 * 64];   // 2 x 8 KB
    __shared__ __align__(16) unsigned Vt2[2][64 * 36];  // 2 x 9 KB
    __shared__ __align__(16) ushort_t Ps[64 * 72];      // 9 KB
    __shared__ __align__(16) float r3s[64][4];

    const int bx = blockIdx.x;
    const int ks = bx & 1;
    const int qt = (bx >> 1) & 15;
    const int h  = (bx >> 5) % HH;
    const int b  = bx / (32 * HH);
    const int q0 = qt * 64;
    const int t  = threadIdx.x;
    const int w  = t >> 6;
    const int l  = t & 63;
    const int l15  = l & 15;
    const int quad = l >> 4;

    // staging index precompute
    const int sr  = t >> 3;          // K row 0..31 (+32 for second)
    const int scp = t & 7;           // K phys chunk
    const int vkp = t >> 3;          // V kpair 0..31
    const int vdg = t & 7;           // V d-group
    const int vkps = vkp ^ (vdg * 4);

    const size_t qrow = (size_t)(b * SS + q0 + w * 16 + l15) * (3 * DD) + h * HD;
    const short8 qf0 = *(const short8*)(qkv + qrow + quad * 8);
    const short8 qf1 = *(const short8*)(qkv + qrow + 32 + quad * 8);

    {
        float rv[3];
#pragma unroll
        for (int c = 0; c < 3; ++c) {
            const float* a = rel_A + c * HD + quad * 8;
            float acc = 0.f;
#pragma unroll
            for (int j = 0; j < 8; ++j) acc += bf2f(qf0[j]) * a[j];
#pragma unroll
            for (int j = 0; j < 8; ++j) acc += bf2f(qf1[j]) * a[32 + j];
            acc += __shfl_xor(acc, 16);
            acc += __shfl_xor(acc, 32);
            rv[c] = acc;
        }
        if (quad == 0) {
            float4 f4 = make_float4(rv[0], rv[1], rv[2], -2.4e31f);
            *(float4*)&r3s[w * 16 + l15][0] = f4;
        }
    }

    float l_run[4] = {0.f, 0.f, 0.f, 0.f};
    f32x4 oacc[4] = {};

    const int kt0 = ks * 8;
    // ---- prologue: stage tile kt0 into buf 0 ----
    short8 va, vb;
    {
        const int k0 = kt0 * 64;
        const int cl  = scp ^ (sr & 7);
        const ushort_t* g = qkv + (size_t)(b * SS + k0 + sr) * (3 * DD) + DD + h * HD + cl * 8;
        __builtin_amdgcn_global_load_lds(
            (const __attribute__((address_space(1))) unsigned*)g,
            (__attribute__((address_space(3))) unsigned*)(&Ks[0][0] + (size_t)t * 8), 16, 0, 0);
        const int r2  = sr + 32;
        const int cl2 = scp ^ (r2 & 7);
        const ushort_t* g2 = qkv + (size_t)(b * SS + k0 + r2) * (3 * DD) + DD + h * HD + cl2 * 8;
        __builtin_amdgcn_global_load_lds(
            (const __attribute__((address_space(1))) unsigned*)g2,
            (__attribute__((address_space(3))) unsigned*)(&Ks[0][0] + (size_t)(t + 256) * 8), 16, 0, 0);
        const ushort_t* gv = qkv + (size_t)(b * SS + k0 + 2 * vkp) * (3 * DD) + 2 * DD + h * HD + vdg * 8;
        va = *(const short8*)gv;
        vb = *(const short8*)(gv + 3 * DD);
#pragma unroll
        for (int i = 0; i < 8; ++i)
            Vt2[0][(size_t)(vdg * 8 + i) * 36 + vkps] =
                (unsigned)(ushort_t)va[i] | ((unsigned)(ushort_t)vb[i] << 16);
    }
    __syncthreads();
    float4 r3v[4];
#pragma unroll
    for (int reg = 0; reg < 4; ++reg)
        r3v[reg] = *(const float4*)&r3s[w * 16 + quad * 4 + reg][0];

    for (int i8 = 0; i8 < 8; ++i8) {
        const int kt  = kt0 + i8;
        const int cur = i8 & 1;
        const bool more = (i8 + 1 < 8);
        // ---- issue next tile's K dma + V reg loads ----
        if (more) {
            const int k0 = (kt + 1) * 64;
            const int nb = cur ^ 1;
            const int cl  = scp ^ (sr & 7);
            const ushort_t* g = qkv + (size_t)(b * SS + k0 + sr) * (3 * DD) + DD + h * HD + cl * 8;
            __builtin_amdgcn_global_load_lds(
                (const __attribute__((address_space(1))) unsigned*)g,
                (__attribute__((address_space(3))) unsigned*)(&Ks[nb][0] + (size_t)t * 8), 16, 0, 0);
            const int r2  = sr + 32;
            const int cl2 = scp ^ (r2 & 7);
            const ushort_t* g2 = qkv + (size_t)(b * SS + k0 + r2) * (3 * DD) + DD + h * HD + cl2 * 8;
            __builtin_amdgcn_global_load_lds(
                (const __attribute__((address_space(1))) unsigned*)g2,
                (__attribute__((address_space(3))) unsigned*)(&Ks[nb][0] + (size_t)(t + 256) * 8), 16, 0, 0);
            const ushort_t* gv = qkv + (size_t)(b * SS + k0 + 2 * vkp) * (3 * DD) + 2 * DD + h * HD + vdg * 8;
            va = *(const short8*)gv;
            vb = *(const short8*)(gv + 3 * DD);
        }

        // ---- S = Q K^T (from Ks[cur]) ----
        f32x4 sacc[4] = {};
#pragma unroll
        for (int kc = 0; kc < 2; ++kc) {
            const short8 qv = kc ? qf1 : qf0;
#pragma unroll
            for (int nt = 0; nt < 4; ++nt) {
                const int row = nt * 16 + l15;
                const int cp  = (kc * 4 + quad) ^ (row & 7);
                const short8 kf = *(const short8*)(&Ks[cur][0] + (size_t)row * 64 + cp * 8);
                sacc[nt] = __builtin_amdgcn_mfma_f32_16x16x32_bf16(qv, kf, sacc[nt], 0, 0, 0);
            }
        }

        // ---- rel/mask + direct exp ----
#pragma unroll
        for (int reg = 0; reg < 4; ++reg) {
            const int qloc = w * 16 + quad * 4 + reg;
            const unsigned cds = codes[((size_t)(b * SS + q0 + qloc) * 16 + kt) * 16 + l15];
            const float4 r4 = r3v[reg];
#pragma unroll
            for (int nt = 0; nt < 4; ++nt) {
                const unsigned c = (cds >> (8 * nt)) & 0xff;
                float rvv = (c == 0) ? r4.x : (c == 1) ? r4.y : (c == 2) ? r4.z : r4.w;
                const float p = __expf((sacc[nt][reg] + rvv) * 0.125f);
                l_run[reg] += p;
                Ps[(size_t)qloc * 72 + nt * 16 + l15] = f2bf_rne(p);
            }
        }

        // ---- O += P V (from Vt2[cur]; per-wave Ps, no barrier) ----
#pragma unroll
        for (int kc = 0; kc < 2; ++kc) {
            const short8 pf = *(const short8*)(Ps + (size_t)(w * 16 + l15) * 72 + kc * 32 + quad * 8);
#pragma unroll
            for (int dt = 0; dt < 4; ++dt) {
                const int d  = dt * 16 + l15;
                const int dg = d >> 3;
                const int kps0 = (kc * 16 + quad * 4) ^ ((dg & 7) * 4);
                const short8 vf = *(const short8*)((const ushort_t*)&Vt2[cur][(size_t)d * 36 + kps0]);
                oacc[dt] = __builtin_amdgcn_mfma_f32_16x16x32_bf16(pf, vf, oacc[dt], 0, 0, 0);
            }
        }

        // ---- write next V tile into Vt2[!cur] (loads arrived during compute)
        if (more) {
            const int nb = cur ^ 1;
#pragma unroll
            for (int i = 0; i < 8; ++i)
                Vt2[nb][(size_t)(vdg * 8 + i) * 36 + vkps] =
                    (unsigned)(ushort_t)va[i] | ((unsigned)(ushort_t)vb[i] << 16);
            __syncthreads();   // K dma drained, V writes visible, prev reads done
        }
    }

    // ---- epilogue: reduce l across the 16-lane row group; emit partials ----
    ushort_t* Op = Opart + (size_t)ks * BSD;
    float* lp = lpart + (size_t)ks * BS2 * HH;
#pragma unroll
    for (int reg = 0; reg < 4; ++reg) {
        float ls = l_run[reg];
        ls += __shfl_xor(ls, 1);
        ls += __shfl_xor(ls, 2);
        ls += __shfl_xor(ls, 4);
        ls += __shfl_xor(ls, 8);
        const int orow = b * SS + q0 + w * 16 + quad * 4 + reg;
#pragma unroll
        for (int dt = 0; dt < 4; ++dt)
            Op[(size_t)orow * DD + h * HD + dt * 16 + l15] = f2bf_rne(oacc[dt][reg]);
        if (l15 == 0) lp[(size_t)orow * HH + h] = ls;
    }
}

// ---------------------------------------------------------------------------
// attn_merge: att_bf = (O0 + O1) / (l0 + l1), bf16 partials in, bf16 out.
// ---------------------------------------------------------------------------
__global__ __launch_bounds__(256) void attn_merge(
    const ushort_t* __restrict__ Opart, const float* __restrict__ lpart,
    ushort_t* __restrict__ att_bf)
{
    int i = blockIdx.x * 256 + threadIdx.x;
    int row = (i * 4) / DD;
    int h   = ((i * 4) % DD) >> 6;
    float l0 = lpart[(size_t)row * HH + h];
    float l1 = lpart[(size_t)BS2 * HH + (size_t)row * HH + h];
    float inv = 1.0f / (l0 + l1);
    ushort4 a = ((const ushort4*)Opart)[i];
    ushort4 b = ((const ushort4*)(Opart + BSD))[i];
    ushort4 o;
    o.x = f2bf_rne((bf2f(a.x) + bf2f(b.x)) * inv);
    o.y = f2bf_rne((bf2f(a.y) + bf2f(b.y)) * inv);
    o.z = f2bf_rne((bf2f(a.z) + bf2f(b.z)) * inv);
    o.w = f2bf_rne((bf2f(a.w) + bf2f(b.w)) * inv);
    ((ushort4*)att_bf)[i] = o;
}

// ---------------------------------------------------------------------------
extern "C" void kernel_launch(void* const* d_in, const int* in_sizes, int n_in,
                              void* d_out, int out_size, void* d_ws, size_t ws_size,
                              hipStream_t stream) {
    const float* inp   = (const float*)d_in[0];
    const uchar_t* amask = (const uchar_t*)d_in[1];
    const int*   relm  = (const int*)d_in[2];
    const float* qkv_w = (const float*)d_in[3];
    const float* rel_A = (const float*)d_in[4];
    const float* o_w   = (const float*)d_in[5];
    const float* w1    = (const float*)d_in[6];
    const float* b1    = (const float*)d_in[7];
    const float* w2    = (const float*)d_in[8];
    const float* b2    = (const float*)d_in[9];
    const float* ln1_g = (const float*)d_in[10];
    const float* ln1_b = (const float*)d_in[11];
    const float* ln2_g = (const float*)d_in[12];
    const float* ln2_b = (const float*)d_in[13];
    float* out = (float*)d_out;

    // workspace layout (weight bf16 buffers MUST stay contiguous for cvt)
    char* p = (char*)d_ws;
    ushort_t* x_bf   = (ushort_t*)p; p += BSD * 2;
    ushort_t* att_bf = (ushort_t*)p; p += BSD * 2;
    ushort_t* h_bf   = (ushort_t*)p; p += BSD * 2;
    ushort_t* ff_bf  = (ushort_t*)p; p += (size_t)BS2 * DFF * 2;
    ushort_t* qkvw_bf= (ushort_t*)p; p += (size_t)3 * DD * DD * 2;
    ushort_t* ow_bf  = (ushort_t*)p; p += (size_t)DD * DD * 2;
    ushort_t* w1_bf  = (ushort_t*)p; p += (size_t)DFF * DD * 2;
    ushort_t* w2_bf  = (ushort_t*)p; p += (size_t)DD * DFF * 2;
    ushort_t* qkv_bf = (ushort_t*)p; p += (size_t)BS2 * 3 * DD * 2;
    float*    resid  = (float*)p;    p += BSD * 4;
    ushort_t* pool   = (ushort_t*)p; p += 4 * BSD * 2;   // bf16 partial pool
    ushort_t* Opart  = (ushort_t*)p; p += 2 * BSD * 2;   // bf16 attn partials
    float*    lpart  = (float*)p;    p += (size_t)2 * BS2 * HH * 4;
    unsigned* codes  = (unsigned*)p; p += (size_t)BB * SS * SS;

    // 0. prep: weight cvt + codes + LN1, one launch
    prep_kernel<<<PREP_CVT + PREP_CODES + PREP_LN, 256, 0, stream>>>(
        qkv_w, o_w, w1, w2, qkvw_bf, relm, amask, codes,
        inp, ln1_g, ln1_b, x_bf);

    // 1. QKV = x @ qkv_w.T -> bf16 : grid (18,32) = 576 blocks
    gemm_tile<false, true, false, false>
        <<<dim3(3 * DD / 128, BS2 / 64, 1), 256, 0, stream>>>(
        x_bf, qkvw_bf, nullptr, qkv_bf, BS2, 3 * DD, DD, DD);

    // 2. attention, k-split x2 : grid 768 ; merge -> bf16
    attn_mfma_kernel<<<BB * HH * 16 * 2, 256, 0, stream>>>(
        qkv_bf, codes, rel_A, Opart, lpart);
    attn_merge<<<(int)(BSD / 4 / 256), 256, 0, stream>>>(Opart, lpart, att_bf);

    // 3. o-proj bf16 partials (Z=2) : grid (6,32,2) = 384 blocks
    gemm_tile<false, false, false, true>
        <<<dim3(DD / 128, BS2 / 64, 2), 256, 0, stream>>>(
        att_bf, ow_bf, nullptr, pool, BS2, DD, DD, DD / 2);

    // 4. fused: resid = inp + p0 + p1 ; h_bf = LN2(resid)
    merge2_ln_kernel<<<BS2, 256, 0, stream>>>(
        pool, inp, ln2_g, ln2_b, resid, h_bf);

    // 5. ff = relu(h @ w1.T + b1) -> bf16 : grid (24,32) = 768 blocks
    gemm_tile<true, true, true, false>
        <<<dim3(DFF / 128, BS2 / 64, 1), 256, 0, stream>>>(
        h_bf, w1_bf, b1, ff_bf, BS2, DFF, DD, DD);

    // 6. MLP2 bf16 partials (Z=4) : grid (6,32,4) = 768 blocks
    gemm_tile<false, false, false, true>
        <<<dim3(DD / 128, BS2 / 64, 4), 256, 0, stream>>>(
        ff_bf, w2_bf, nullptr, pool, BS2, DD, DFF, DFF / 4);

    // 7. out = resid + b2 + p0..p3
    merge4_kernel<<<(int)(BSD / 4 / 256), 256, 0, stream>>>(
        pool, resid, b2, out, (int)(BSD / 4));
}